// Round 1
// baseline (560.258 us; speedup 1.0000x reference)
//
#include <hip/hip_runtime.h>
#include <hip/hip_bf16.h>
#include <cstddef>

// ---------------------------------------------------------------------------
// Differential attention (PraxisAttention): per head-pair flash attention with
// ghostmax (softmax-plus-one), O = w0 - lam*w1 (shared V), then GroupNorm over
// each (b,h) S*D chunk. Output reshape is a raw reinterpretation: out.flat ==
// normalized O(B,H,S,D).flat, weight/bias channel c = h*128 + (s*128+d)/2048.
// ---------------------------------------------------------------------------

typedef __bf16 bf16x8 __attribute__((ext_vector_type(8)));
typedef float f32x4 __attribute__((ext_vector_type(4)));

__device__ __forceinline__ bf16x8 cvt8(float4 a, float4 b) {
  bf16x8 r;
  r[0] = (__bf16)a.x; r[1] = (__bf16)a.y; r[2] = (__bf16)a.z; r[3] = (__bf16)a.w;
  r[4] = (__bf16)b.x; r[5] = (__bf16)b.y; r[6] = (__bf16)b.z; r[7] = (__bf16)b.w;
  return r;
}

constexpr int SEQ = 2048;
constexpr int DH  = 128;
constexpr int NH  = 8;    // v heads / groups
constexpr int NH2 = 16;   // q,k heads
constexpr int BM  = 64;   // q rows per block (16 per wave)
constexpr int BK  = 32;   // k/v rows per tile
constexpr float SCALE = 0.088388347648318447f; // 1/sqrt(128)

__global__ __launch_bounds__(256) void attn_kernel(
    const float* __restrict__ q, const float* __restrict__ k,
    const float* __restrict__ v,
    const float* __restrict__ lq1, const float* __restrict__ lk1,
    const float* __restrict__ lq2, const float* __restrict__ lk2,
    float* __restrict__ Obuf, float* __restrict__ stats)
{
  // K staged row-major (stride 136 elems = 272 B, 16B-aligned, +4-bank skew)
  __shared__ __align__(16) __bf16 lds_k[2][32][136];
  // V staged transposed: [d][t], stride 40 elems (80 B)
  __shared__ __align__(16) __bf16 lds_vt[128][40];
  // per-wave P round-trip buffers (C-layout -> A-layout)
  __shared__ __align__(16) __bf16 lds_p[4][2][16][40];

  const int qt = blockIdx.x, h = blockIdx.y, b = blockIdx.z;
  const int qb = qt * BM;
  const int tid = threadIdx.x;
  const int w = tid >> 6, lane = tid & 63;
  const int l15 = lane & 15, quad = lane >> 4;

  // ---- lambda scalar (redundant per wave; 128-elem dots) ----
  float a1 = lq1[lane]*lk1[lane] + lq1[lane+64]*lk1[lane+64];
  float a2 = lq2[lane]*lk2[lane] + lq2[lane+64]*lk2[lane+64];
  #pragma unroll
  for (int off = 1; off < 64; off <<= 1) {
    a1 += __shfl_xor(a1, off);
    a2 += __shfl_xor(a2, off);
  }
  const float lam = __expf(a1) - __expf(a2) + 0.8f;

  const float* qh0 = q + (size_t)(b*NH2 + 2*h) * SEQ * DH;
  const float* qh1 = qh0 + (size_t)SEQ * DH;
  const float* kh0 = k + (size_t)(b*NH2 + 2*h) * SEQ * DH;
  const float* kh1 = kh0 + (size_t)SEQ * DH;
  const float* vh  = v + (size_t)(b*NH + h) * SEQ * DH;

  // ---- Q fragments, A-layout: lane holds Q[qb+w*16+l15][kd*32+quad*8 ..+7] ----
  bf16x8 qf[2][4];
  {
    const int qrow = qb + w*16 + l15;
    #pragma unroll
    for (int sh = 0; sh < 2; ++sh) {
      const float* src = (sh ? qh1 : qh0) + (size_t)qrow * DH + quad*8;
      #pragma unroll
      for (int kd = 0; kd < 4; ++kd) {
        float4 f0 = *(const float4*)(src + kd*32);
        float4 f1 = *(const float4*)(src + kd*32 + 4);
        qf[sh][kd] = cvt8(f0, f1);
      }
    }
  }

  f32x4 oacc[2][8];
  #pragma unroll
  for (int sh = 0; sh < 2; ++sh)
    #pragma unroll
    for (int nt = 0; nt < 8; ++nt)
      oacc[sh][nt] = (f32x4){0.f, 0.f, 0.f, 0.f};

  // online ghost-softmax state: m=0 (ghost logit), l=1 (=exp(0-0))
  float mst[2][4] = {{0.f,0.f,0.f,0.f},{0.f,0.f,0.f,0.f}};
  float lst[2][4] = {{1.f,1.f,1.f,1.f},{1.f,1.f,1.f,1.f}};

  // staging thread mapping
  const int krow = tid >> 2, ksh = krow >> 5, kr = krow & 31;
  const int kd0 = (tid & 3) * 32;
  const float* ksrc0 = (ksh ? kh1 : kh0) + kd0;
  const int vt = tid >> 3, vd = (tid & 7) * 16;

  const int nsteps = (qb + BM) / BK;
  for (int st = 0; st < nsteps; ++st) {
    const int kbt = st * BK;

    // ---- stage K (both sub-heads) + V^T into LDS as bf16 ----
    {
      const float* sp = ksrc0 + (size_t)(kbt + kr) * DH;
      #pragma unroll
      for (int c = 0; c < 4; ++c) {
        float4 f0 = *(const float4*)(sp + c*8);
        float4 f1 = *(const float4*)(sp + c*8 + 4);
        *(bf16x8*)&lds_k[ksh][kr][kd0 + c*8] = cvt8(f0, f1);
      }
      const float* vp = vh + (size_t)(kbt + vt) * DH + vd;
      #pragma unroll
      for (int c = 0; c < 4; ++c) {
        float4 f = *(const float4*)(vp + c*4);
        lds_vt[vd + c*4 + 0][vt] = (__bf16)f.x;
        lds_vt[vd + c*4 + 1][vt] = (__bf16)f.y;
        lds_vt[vd + c*4 + 2][vt] = (__bf16)f.z;
        lds_vt[vd + c*4 + 3][vt] = (__bf16)f.w;
      }
    }
    __syncthreads();

    // ---- S = Q K^T : per sub-head, two 16x16 n-tiles, 4 k-steps over D ----
    f32x4 sacc[2][2];
    #pragma unroll
    for (int sh = 0; sh < 2; ++sh)
      #pragma unroll
      for (int n = 0; n < 2; ++n)
        sacc[sh][n] = (f32x4){0.f, 0.f, 0.f, 0.f};

    #pragma unroll
    for (int sh = 0; sh < 2; ++sh)
      #pragma unroll
      for (int n = 0; n < 2; ++n)
        #pragma unroll
        for (int kd = 0; kd < 4; ++kd) {
          bf16x8 bf = *(const bf16x8*)&lds_k[sh][n*16 + l15][kd*32 + quad*8];
          sacc[sh][n] = __builtin_amdgcn_mfma_f32_16x16x32_bf16(
              qf[sh][kd], bf, sacc[sh][n], 0, 0, 0);
        }

    // ---- online ghost-softmax update + P (bf16) to LDS ----
    const int qrow0 = qb + w*16 + quad*4;
    const int c0 = kbt + l15, c1 = c0 + 16;
    #pragma unroll
    for (int sh = 0; sh < 2; ++sh) {
      #pragma unroll
      for (int r = 0; r < 4; ++r) {
        float s0 = sacc[sh][0][r] * SCALE;
        float s1 = sacc[sh][1][r] * SCALE;
        const int qr = qrow0 + r;
        if (c0 > qr) s0 = -1e30f;
        if (c1 > qr) s1 = -1e30f;
        float mx = fmaxf(s0, s1);
        #pragma unroll
        for (int off = 1; off < 16; off <<= 1)
          mx = fmaxf(mx, __shfl_xor(mx, off));
        const float mnew = fmaxf(mst[sh][r], mx);
        const float alpha = __expf(mst[sh][r] - mnew);
        mst[sh][r] = mnew;
        const float p0 = __expf(s0 - mnew);
        const float p1 = __expf(s1 - mnew);
        float rs = p0 + p1;
        #pragma unroll
        for (int off = 1; off < 16; off <<= 1)
          rs += __shfl_xor(rs, off);
        lst[sh][r] = lst[sh][r] * alpha + rs;
        #pragma unroll
        for (int nt = 0; nt < 8; ++nt)
          oacc[sh][nt][r] *= alpha;
        lds_p[w][sh][quad*4 + r][l15]      = (__bf16)p0;
        lds_p[w][sh][quad*4 + r][l15 + 16] = (__bf16)p1;
      }
    }

    // ---- O += P V : P in A-layout from LDS, V^T supplies B-layout ----
    {
      bf16x8 pf0 = *(const bf16x8*)&lds_p[w][0][l15][quad*8];
      bf16x8 pf1 = *(const bf16x8*)&lds_p[w][1][l15][quad*8];
      #pragma unroll
      for (int nt = 0; nt < 8; ++nt) {
        bf16x8 vf = *(const bf16x8*)&lds_vt[nt*16 + l15][quad*8];
        oacc[0][nt] = __builtin_amdgcn_mfma_f32_16x16x32_bf16(pf0, vf, oacc[0][nt], 0, 0, 0);
        oacc[1][nt] = __builtin_amdgcn_mfma_f32_16x16x32_bf16(pf1, vf, oacc[1][nt], 0, 0, 0);
      }
    }
    __syncthreads();
  }

  // ---- epilogue: O = O0/l0 - lam*O1/l1, write + stats atomics ----
  const int qrow0 = qb + w*16 + quad*4;
  float* obase = Obuf + (size_t)(b*NH + h) * SEQ * DH;
  float sum = 0.f, ss = 0.f;
  #pragma unroll
  for (int r = 0; r < 4; ++r) {
    const float i0 = 1.0f / lst[0][r];
    const float i1 = lam / lst[1][r];
    float* orow = obase + (size_t)(qrow0 + r) * DH + l15;
    #pragma unroll
    for (int nt = 0; nt < 8; ++nt) {
      const float val = oacc[0][nt][r] * i0 - oacc[1][nt][r] * i1;
      orow[nt*16] = val;
      sum += val;
      ss  += val * val;
    }
  }
  #pragma unroll
  for (int off = 1; off < 64; off <<= 1) {
    sum += __shfl_xor(sum, off);
    ss  += __shfl_xor(ss, off);
  }
  if (lane == 0) {
    atomicAdd(&stats[2*(b*NH + h)],     sum);
    atomicAdd(&stats[2*(b*NH + h) + 1], ss);
  }
}

// GroupNorm epilogue, in-place on Obuf (= d_out). Channel c = h*128 + local/2048.
__global__ __launch_bounds__(256) void norm_kernel(
    float* __restrict__ Obuf, const float* __restrict__ stats,
    const float* __restrict__ gw, const float* __restrict__ gb)
{
  const int idx = (blockIdx.x * 256 + threadIdx.x) * 4;
  const int bh = idx >> 18;          // / (2048*128)
  const int local = idx & 262143;
  const float inv = 1.0f / 262144.0f;
  const float mean = stats[2*bh] * inv;
  const float var  = stats[2*bh + 1] * inv - mean * mean;
  const float rstd = rsqrtf(var + 1e-5f);
  const int c = ((bh & 7) << 7) + (local >> 11);
  const float wq = gw[c] * rstd;
  const float bq = gb[c];
  float4 o = *(const float4*)(Obuf + idx);
  float4 r;
  r.x = ((o.x - mean) * wq + bq) * 0.2f;
  r.y = ((o.y - mean) * wq + bq) * 0.2f;
  r.z = ((o.z - mean) * wq + bq) * 0.2f;
  r.w = ((o.w - mean) * wq + bq) * 0.2f;
  *(float4*)(Obuf + idx) = r;
}

extern "C" void kernel_launch(void* const* d_in, const int* in_sizes, int n_in,
                              void* d_out, int out_size, void* d_ws, size_t ws_size,
                              hipStream_t stream) {
  const float* q   = (const float*)d_in[0];
  const float* k   = (const float*)d_in[1];
  const float* v   = (const float*)d_in[2];
  const float* lq1 = (const float*)d_in[3];
  const float* lk1 = (const float*)d_in[4];
  const float* lq2 = (const float*)d_in[5];
  const float* lk2 = (const float*)d_in[6];
  const float* gw  = (const float*)d_in[7];
  const float* gb  = (const float*)d_in[8];
  float* out = (float*)d_out;          // doubles as the O scratch buffer
  float* stats = (float*)d_ws;         // 16 (sum, sumsq) pairs

  hipMemsetAsync(d_ws, 0, 32 * sizeof(float), stream);

  dim3 grid(SEQ / BM, NH, 2);
  attn_kernel<<<grid, 256, 0, stream>>>(q, k, v, lq1, lk1, lq2, lk2, out, stats);

  const int total = 2 * NH * SEQ * DH;     // 4,194,304
  norm_kernel<<<total / 1024, 256, 0, stream>>>(out, stats, gw, gb);
}

// Round 3
// 257.856 us; speedup vs baseline: 2.1728x; 2.1728x over previous
//
#include <hip/hip_runtime.h>
#include <hip/hip_bf16.h>
#include <cstddef>
#include <cstdint>

// ---------------------------------------------------------------------------
// Differential attention (PraxisAttention).
// Round 3 (= round-2 design, compile fixed): pre-converted bf16 Q(*scale)/K/
// V^T in ws, global_load_lds async double-buffered staging with XOR bank
// swizzle, fixed-m (m=0) ghostmax (no in-loop max/shuffles/rescale),
// complementary q-tile pairing for perfect causal load balance.
// ---------------------------------------------------------------------------

typedef __bf16 bf16x8 __attribute__((ext_vector_type(8)));
typedef __bf16 bf16x4 __attribute__((ext_vector_type(4)));
typedef float f32x4 __attribute__((ext_vector_type(4)));

constexpr int SEQ = 2048;
constexpr int DH  = 128;
constexpr int NH  = 8;
constexpr int NH2 = 16;
constexpr float SCALE = 0.088388347648318447f; // 1/sqrt(128)

// ws layout (bytes):
//   [0,256)        : stats (sum, sumsq) per (b,h)
//   [4096, +16MB)  : Qb  bf16 (pre-scaled)  [b][h2][t][d]
//   [.., +16MB)    : Kb  bf16               [b][h2][t][d]
//   [.., +8MB)     : Vtb bf16               [b][h][d][t]
constexpr size_t QK_ELEMS = (size_t)2 * NH2 * SEQ * DH;   // 8,388,608
constexpr size_t V_ELEMS  = (size_t)2 * NH  * SEQ * DH;   // 4,194,304
constexpr size_t OFF_QB   = 4096;
constexpr size_t OFF_KB   = OFF_QB + QK_ELEMS * 2;
constexpr size_t OFF_VT   = OFF_KB + QK_ELEMS * 2;
constexpr size_t WS_NEED  = OFF_VT + V_ELEMS * 2;

__device__ __forceinline__ void load_lds16(const void* g, void* l) {
  __builtin_amdgcn_global_load_lds(
      (const __attribute__((address_space(1))) uint32_t*)g,
      (__attribute__((address_space(3))) uint32_t*)l, 16, 0, 0);
}

__device__ __forceinline__ bf16x8 cvt8(float4 a, float4 b) {
  bf16x8 r;
  r[0] = (__bf16)a.x; r[1] = (__bf16)a.y; r[2] = (__bf16)a.z; r[3] = (__bf16)a.w;
  r[4] = (__bf16)b.x; r[5] = (__bf16)b.y; r[6] = (__bf16)b.z; r[7] = (__bf16)b.w;
  return r;
}

// ---------------- pre-pass: convert (and optionally scale) to bf16 ---------
__global__ __launch_bounds__(256) void cvt_kernel(
    const float* __restrict__ in, __bf16* __restrict__ out, float scale)
{
  const size_t i = ((size_t)blockIdx.x * 256 + threadIdx.x) * 8;
  float4 a = *(const float4*)(in + i);
  float4 b = *(const float4*)(in + i + 4);
  a.x *= scale; a.y *= scale; a.z *= scale; a.w *= scale;
  b.x *= scale; b.y *= scale; b.z *= scale; b.w *= scale;
  *(bf16x8*)(out + i) = cvt8(a, b);
}

// ---------------- pre-pass: V -> V^T (bf16) --------------------------------
__global__ __launch_bounds__(256) void vt_kernel(
    const float* __restrict__ v, __bf16* __restrict__ vt)
{
  __shared__ float tile[32][33];
  const int tt = blockIdx.x, dt = blockIdx.y, bh = blockIdx.z;
  const int tr = threadIdx.x >> 3, tc = (threadIdx.x & 7) * 4;
  const float* src = v + ((size_t)bh * SEQ + tt * 32) * DH + dt * 32;
  float4 f = *(const float4*)(src + (size_t)tr * DH + tc);
  tile[tr][tc + 0] = f.x; tile[tr][tc + 1] = f.y;
  tile[tr][tc + 2] = f.z; tile[tr][tc + 3] = f.w;
  __syncthreads();
  // write Vt[d][t]: row d = dt*32+tr, t = tt*32 + tc..tc+3
  __bf16* dst = vt + ((size_t)bh * DH + dt * 32 + tr) * SEQ + tt * 32 + tc;
  bf16x4 o;
  o[0] = (__bf16)tile[tc + 0][tr];
  o[1] = (__bf16)tile[tc + 1][tr];
  o[2] = (__bf16)tile[tc + 2][tr];
  o[3] = (__bf16)tile[tc + 3][tr];
  *(bf16x4*)dst = o;
}

// ---------------- main attention kernel ------------------------------------
__global__ __launch_bounds__(256) void attn2_kernel(
    const __bf16* __restrict__ Qb, const __bf16* __restrict__ Kb,
    const __bf16* __restrict__ Vtb,
    const float* __restrict__ lq1, const float* __restrict__ lk1,
    const float* __restrict__ lq2, const float* __restrict__ lk2,
    float* __restrict__ Obuf, float* __restrict__ stats)
{
  // packed (no pad) for global_load_lds; XOR-swizzled chunk placement
  __shared__ __align__(16) __bf16 ldsK[2][2][32][128];  // [buf][sh][kr][d] 16KB/buf
  __shared__ __align__(16) __bf16 ldsVt[2][128][32];    // [buf][d][t]      8KB/buf
  __shared__ __align__(16) __bf16 ldsP[4][2][16][40];   // [wave][sh][r][t] pad40

  const int pi = blockIdx.x;   // 0..15 pair index
  const int bh = blockIdx.y;   // 0..15
  const int b = bh >> 3, h = bh & 7;
  const int tid = threadIdx.x;
  const int w = tid >> 6, lane = tid & 63;
  const int l15 = lane & 15, quad = lane >> 4;

  // ---- lambda scalar ----
  float a1 = lq1[lane]*lk1[lane] + lq1[lane+64]*lk1[lane+64];
  float a2 = lq2[lane]*lk2[lane] + lq2[lane+64]*lk2[lane+64];
  #pragma unroll
  for (int off = 1; off < 64; off <<= 1) {
    a1 += __shfl_xor(a1, off);
    a2 += __shfl_xor(a2, off);
  }
  const float lam = __expf(a1) - __expf(a2) + 0.8f;

  const size_t headQK = (size_t)(b*NH2 + 2*h) * SEQ * DH;
  const __bf16* Qh  = Qb + headQK;
  const __bf16* Kh  = Kb + headQK;
  const __bf16* Vth = Vtb + (size_t)(b*NH + h) * DH * SEQ;

  // ---- per-lane staging source offsets (element units, swizzled) ----
  size_t goffK[4];
  #pragma unroll
  for (int i = 0; i < 4; ++i) {
    const int R  = w*16 + i*4 + quad;      // flat row 0..63
    const int sh = R >> 5, kr = R & 31;
    const int cs = lane & 15;              // LDS chunk slot
    goffK[i] = ((size_t)sh * SEQ + kr) * DH + ((cs ^ (kr & 15)) * 8);
  }
  size_t goffV[2];
  #pragma unroll
  for (int i = 0; i < 2; ++i) {
    const int d  = w*32 + i*16 + (lane >> 2);
    const int cs = lane & 3;
    goffV[i] = (size_t)d * SEQ + ((cs ^ (d & 3)) * 8);
  }

  __bf16* ldsKb0 = &ldsK[0][0][0][0];
  __bf16* ldsVb0 = &ldsVt[0][0][0];

  const int qts[2] = {31 - pi, pi};

  for (int t2 = 0; t2 < 2; ++t2) {
    const int qt = qts[t2], qb = qt * 64, nsteps = 2 * (qt + 1);

    // Q fragments (pre-scaled bf16): A-layout
    const int qrow = qb + w*16 + l15;
    bf16x8 qf[2][4];
    #pragma unroll
    for (int sh = 0; sh < 2; ++sh)
      #pragma unroll
      for (int kd = 0; kd < 4; ++kd)
        qf[sh][kd] = *(const bf16x8*)(Qh + (size_t)sh*SEQ*DH + (size_t)qrow*DH + kd*32 + quad*8);

    f32x4 oacc[2][8];
    float lsum[2][4];
    #pragma unroll
    for (int sh = 0; sh < 2; ++sh) {
      #pragma unroll
      for (int nt = 0; nt < 8; ++nt) oacc[sh][nt] = (f32x4){0.f,0.f,0.f,0.f};
      #pragma unroll
      for (int r = 0; r < 4; ++r) lsum[sh][r] = 0.f;
    }

    // stage step 0 into buf 0
    {
      const __bf16* kg = Kh;
      #pragma unroll
      for (int i = 0; i < 4; ++i)
        load_lds16(kg + goffK[i], ldsKb0 + w*2048 + i*512);
      const __bf16* vg = Vth;
      #pragma unroll
      for (int i = 0; i < 2; ++i)
        load_lds16(vg + goffV[i], ldsVb0 + w*1024 + i*512);
    }
    __syncthreads();

    for (int st = 0; st < nsteps; ++st) {
      const int cur = st & 1;
      const int kbt = st * 32;

      // async prefetch next tile into the other buffer
      if (st + 1 < nsteps) {
        const int nxt = cur ^ 1;
        const __bf16* kg = Kh + (size_t)(kbt + 32) * DH;
        #pragma unroll
        for (int i = 0; i < 4; ++i)
          load_lds16(kg + goffK[i], ldsKb0 + (size_t)nxt*8192 + w*2048 + i*512);
        const __bf16* vg = Vth + (kbt + 32);
        #pragma unroll
        for (int i = 0; i < 2; ++i)
          load_lds16(vg + goffV[i], ldsVb0 + (size_t)nxt*4096 + w*1024 + i*512);
      }

      // ---- S = Q K^T ----
      f32x4 sacc[2][2];
      #pragma unroll
      for (int sh = 0; sh < 2; ++sh)
        #pragma unroll
        for (int n = 0; n < 2; ++n)
          sacc[sh][n] = (f32x4){0.f,0.f,0.f,0.f};
      #pragma unroll
      for (int sh = 0; sh < 2; ++sh)
        #pragma unroll
        for (int n = 0; n < 2; ++n)
          #pragma unroll
          for (int kd = 0; kd < 4; ++kd) {
            bf16x8 kf = *(const bf16x8*)&ldsK[cur][sh][n*16 + l15][((kd*4 + quad) ^ l15) * 8];
            sacc[sh][n] = __builtin_amdgcn_mfma_f32_16x16x32_bf16(qf[sh][kd], kf, sacc[sh][n], 0, 0, 0);
          }

      // ---- fixed-m ghostmax: p = exp(s) (masked), accumulate l per-lane ----
      const int qrow0 = qb + w*16 + quad*4;
      #pragma unroll
      for (int sh = 0; sh < 2; ++sh)
        #pragma unroll
        for (int r = 0; r < 4; ++r) {
          const int qr = qrow0 + r;
          const float p0 = (kbt + l15      <= qr) ? __expf(sacc[sh][0][r]) : 0.f;
          const float p1 = (kbt + l15 + 16 <= qr) ? __expf(sacc[sh][1][r]) : 0.f;
          lsum[sh][r] += p0 + p1;
          ldsP[w][sh][quad*4 + r][l15]      = (__bf16)p0;
          ldsP[w][sh][quad*4 + r][l15 + 16] = (__bf16)p1;
        }

      // ---- O += P V ----
      {
        bf16x8 pf0 = *(const bf16x8*)&ldsP[w][0][l15][quad*8];
        bf16x8 pf1 = *(const bf16x8*)&ldsP[w][1][l15][quad*8];
        #pragma unroll
        for (int nt = 0; nt < 8; ++nt) {
          bf16x8 vf = *(const bf16x8*)&ldsVt[cur][nt*16 + l15][(quad ^ (l15 & 3)) * 8];
          oacc[0][nt] = __builtin_amdgcn_mfma_f32_16x16x32_bf16(pf0, vf, oacc[0][nt], 0, 0, 0);
          oacc[1][nt] = __builtin_amdgcn_mfma_f32_16x16x32_bf16(pf1, vf, oacc[1][nt], 0, 0, 0);
        }
      }
      __syncthreads();
    }

    // ---- epilogue ----
    #pragma unroll
    for (int sh = 0; sh < 2; ++sh)
      #pragma unroll
      for (int r = 0; r < 4; ++r) {
        float vsum = lsum[sh][r];
        #pragma unroll
        for (int off = 1; off < 16; off <<= 1) vsum += __shfl_xor(vsum, off);
        lsum[sh][r] = vsum + 1.0f;   // ghost logit
      }

    const int qrow0 = qb + w*16 + quad*4;
    float* obase = Obuf + (size_t)(b*NH + h) * SEQ * DH;
    float sum = 0.f, ss = 0.f;
    #pragma unroll
    for (int r = 0; r < 4; ++r) {
      const float i0 = 1.0f / lsum[0][r];
      const float i1 = lam / lsum[1][r];
      float* orow = obase + (size_t)(qrow0 + r) * DH + l15;
      #pragma unroll
      for (int nt = 0; nt < 8; ++nt) {
        const float val = oacc[0][nt][r] * i0 - oacc[1][nt][r] * i1;
        orow[nt*16] = val;
        sum += val;
        ss  += val * val;
      }
    }
    #pragma unroll
    for (int off = 1; off < 64; off <<= 1) {
      sum += __shfl_xor(sum, off);
      ss  += __shfl_xor(ss, off);
    }
    if (lane == 0) {
      atomicAdd(&stats[2*(b*NH + h)],     sum);
      atomicAdd(&stats[2*(b*NH + h) + 1], ss);
    }
  }
}

// ---------------- fallback (round-1) attention kernel ----------------------
__global__ __launch_bounds__(256) void attn_fb_kernel(
    const float* __restrict__ q, const float* __restrict__ k,
    const float* __restrict__ v,
    const float* __restrict__ lq1, const float* __restrict__ lk1,
    const float* __restrict__ lq2, const float* __restrict__ lk2,
    float* __restrict__ Obuf, float* __restrict__ stats)
{
  __shared__ __align__(16) __bf16 lds_k[2][32][136];
  __shared__ __align__(16) __bf16 lds_vt[128][40];
  __shared__ __align__(16) __bf16 lds_p[4][2][16][40];

  const int qt = blockIdx.x, h = blockIdx.y, b = blockIdx.z;
  const int qb = qt * 64;
  const int tid = threadIdx.x;
  const int w = tid >> 6, lane = tid & 63;
  const int l15 = lane & 15, quad = lane >> 4;

  float a1 = lq1[lane]*lk1[lane] + lq1[lane+64]*lk1[lane+64];
  float a2 = lq2[lane]*lk2[lane] + lq2[lane+64]*lk2[lane+64];
  #pragma unroll
  for (int off = 1; off < 64; off <<= 1) {
    a1 += __shfl_xor(a1, off);
    a2 += __shfl_xor(a2, off);
  }
  const float lam = __expf(a1) - __expf(a2) + 0.8f;

  const float* qh0 = q + (size_t)(b*NH2 + 2*h) * SEQ * DH;
  const float* qh1 = qh0 + (size_t)SEQ * DH;
  const float* kh0 = k + (size_t)(b*NH2 + 2*h) * SEQ * DH;
  const float* kh1 = kh0 + (size_t)SEQ * DH;
  const float* vh  = v + (size_t)(b*NH + h) * SEQ * DH;

  bf16x8 qf[2][4];
  {
    const int qrow = qb + w*16 + l15;
    #pragma unroll
    for (int sh = 0; sh < 2; ++sh) {
      const float* src = (sh ? qh1 : qh0) + (size_t)qrow * DH + quad*8;
      #pragma unroll
      for (int kd = 0; kd < 4; ++kd) {
        float4 f0 = *(const float4*)(src + kd*32);
        float4 f1 = *(const float4*)(src + kd*32 + 4);
        qf[sh][kd] = cvt8(f0, f1);
      }
    }
  }

  f32x4 oacc[2][8];
  #pragma unroll
  for (int sh = 0; sh < 2; ++sh)
    #pragma unroll
    for (int nt = 0; nt < 8; ++nt)
      oacc[sh][nt] = (f32x4){0.f,0.f,0.f,0.f};

  float mst[2][4] = {{0.f,0.f,0.f,0.f},{0.f,0.f,0.f,0.f}};
  float lst[2][4] = {{1.f,1.f,1.f,1.f},{1.f,1.f,1.f,1.f}};

  const int krow = tid >> 2, ksh = krow >> 5, kr = krow & 31;
  const int kd0 = (tid & 3) * 32;
  const float* ksrc0 = (ksh ? kh1 : kh0) + kd0;
  const int vt = tid >> 3, vd = (tid & 7) * 16;

  const int nsteps = (qb + 64) / 32;
  for (int st = 0; st < nsteps; ++st) {
    const int kbt = st * 32;
    {
      const float* sp = ksrc0 + (size_t)(kbt + kr) * DH;
      #pragma unroll
      for (int c = 0; c < 4; ++c) {
        float4 f0 = *(const float4*)(sp + c*8);
        float4 f1 = *(const float4*)(sp + c*8 + 4);
        *(bf16x8*)&lds_k[ksh][kr][kd0 + c*8] = cvt8(f0, f1);
      }
      const float* vp = vh + (size_t)(kbt + vt) * DH + vd;
      #pragma unroll
      for (int c = 0; c < 4; ++c) {
        float4 f = *(const float4*)(vp + c*4);
        lds_vt[vd + c*4 + 0][vt] = (__bf16)f.x;
        lds_vt[vd + c*4 + 1][vt] = (__bf16)f.y;
        lds_vt[vd + c*4 + 2][vt] = (__bf16)f.z;
        lds_vt[vd + c*4 + 3][vt] = (__bf16)f.w;
      }
    }
    __syncthreads();

    f32x4 sacc[2][2];
    #pragma unroll
    for (int sh = 0; sh < 2; ++sh)
      #pragma unroll
      for (int n = 0; n < 2; ++n)
        sacc[sh][n] = (f32x4){0.f,0.f,0.f,0.f};

    #pragma unroll
    for (int sh = 0; sh < 2; ++sh)
      #pragma unroll
      for (int n = 0; n < 2; ++n)
        #pragma unroll
        for (int kd = 0; kd < 4; ++kd) {
          bf16x8 bf = *(const bf16x8*)&lds_k[sh][n*16 + l15][kd*32 + quad*8];
          sacc[sh][n] = __builtin_amdgcn_mfma_f32_16x16x32_bf16(qf[sh][kd], bf, sacc[sh][n], 0, 0, 0);
        }

    const int qrow0 = qb + w*16 + quad*4;
    const int c0 = kbt + l15, c1 = c0 + 16;
    #pragma unroll
    for (int sh = 0; sh < 2; ++sh) {
      #pragma unroll
      for (int r = 0; r < 4; ++r) {
        float s0 = sacc[sh][0][r] * SCALE;
        float s1 = sacc[sh][1][r] * SCALE;
        const int qr = qrow0 + r;
        if (c0 > qr) s0 = -1e30f;
        if (c1 > qr) s1 = -1e30f;
        float mx = fmaxf(s0, s1);
        #pragma unroll
        for (int off = 1; off < 16; off <<= 1)
          mx = fmaxf(mx, __shfl_xor(mx, off));
        const float mnew = fmaxf(mst[sh][r], mx);
        const float alpha = __expf(mst[sh][r] - mnew);
        mst[sh][r] = mnew;
        const float p0 = __expf(s0 - mnew);
        const float p1 = __expf(s1 - mnew);
        float rs = p0 + p1;
        #pragma unroll
        for (int off = 1; off < 16; off <<= 1)
          rs += __shfl_xor(rs, off);
        lst[sh][r] = lst[sh][r] * alpha + rs;
        #pragma unroll
        for (int nt = 0; nt < 8; ++nt)
          oacc[sh][nt][r] *= alpha;
        lds_p[w][sh][quad*4 + r][l15]      = (__bf16)p0;
        lds_p[w][sh][quad*4 + r][l15 + 16] = (__bf16)p1;
      }
    }

    {
      bf16x8 pf0 = *(const bf16x8*)&lds_p[w][0][l15][quad*8];
      bf16x8 pf1 = *(const bf16x8*)&lds_p[w][1][l15][quad*8];
      #pragma unroll
      for (int nt = 0; nt < 8; ++nt) {
        bf16x8 vf = *(const bf16x8*)&lds_vt[nt*16 + l15][quad*8];
        oacc[0][nt] = __builtin_amdgcn_mfma_f32_16x16x32_bf16(pf0, vf, oacc[0][nt], 0, 0, 0);
        oacc[1][nt] = __builtin_amdgcn_mfma_f32_16x16x32_bf16(pf1, vf, oacc[1][nt], 0, 0, 0);
      }
    }
    __syncthreads();
  }

  const int qrow0 = qb + w*16 + quad*4;
  float* obase = Obuf + (size_t)(b*NH + h) * SEQ * DH;
  float sum = 0.f, ss = 0.f;
  #pragma unroll
  for (int r = 0; r < 4; ++r) {
    const float i0 = 1.0f / lst[0][r];
    const float i1 = lam / lst[1][r];
    float* orow = obase + (size_t)(qrow0 + r) * DH + l15;
    #pragma unroll
    for (int nt = 0; nt < 8; ++nt) {
      const float val = oacc[0][nt][r] * i0 - oacc[1][nt][r] * i1;
      orow[nt*16] = val;
      sum += val;
      ss  += val * val;
    }
  }
  #pragma unroll
  for (int off = 1; off < 64; off <<= 1) {
    sum += __shfl_xor(sum, off);
    ss  += __shfl_xor(ss, off);
  }
  if (lane == 0) {
    atomicAdd(&stats[2*(b*NH + h)],     sum);
    atomicAdd(&stats[2*(b*NH + h) + 1], ss);
  }
}

// ---------------- GroupNorm epilogue ---------------------------------------
__global__ __launch_bounds__(256) void norm_kernel(
    float* __restrict__ Obuf, const float* __restrict__ stats,
    const float* __restrict__ gw, const float* __restrict__ gb)
{
  const int idx = (blockIdx.x * 256 + threadIdx.x) * 4;
  const int bh = idx >> 18;
  const int local = idx & 262143;
  const float inv = 1.0f / 262144.0f;
  const float mean = stats[2*bh] * inv;
  const float var  = stats[2*bh + 1] * inv - mean * mean;
  const float rstd = rsqrtf(var + 1e-5f);
  const int c = ((bh & 7) << 7) + (local >> 11);
  const float wq = gw[c] * rstd;
  const float bq = gb[c];
  float4 o = *(const float4*)(Obuf + idx);
  float4 r;
  r.x = ((o.x - mean) * wq + bq) * 0.2f;
  r.y = ((o.y - mean) * wq + bq) * 0.2f;
  r.z = ((o.z - mean) * wq + bq) * 0.2f;
  r.w = ((o.w - mean) * wq + bq) * 0.2f;
  *(float4*)(Obuf + idx) = r;
}

extern "C" void kernel_launch(void* const* d_in, const int* in_sizes, int n_in,
                              void* d_out, int out_size, void* d_ws, size_t ws_size,
                              hipStream_t stream) {
  const float* q   = (const float*)d_in[0];
  const float* k   = (const float*)d_in[1];
  const float* v   = (const float*)d_in[2];
  const float* lq1 = (const float*)d_in[3];
  const float* lk1 = (const float*)d_in[4];
  const float* lq2 = (const float*)d_in[5];
  const float* lk2 = (const float*)d_in[6];
  const float* gw  = (const float*)d_in[7];
  const float* gb  = (const float*)d_in[8];
  float* out = (float*)d_out;
  float* stats = (float*)d_ws;

  (void)hipMemsetAsync(d_ws, 0, 256, stream);

  if (ws_size >= WS_NEED) {
    __bf16* Qb  = (__bf16*)((char*)d_ws + OFF_QB);
    __bf16* Kb  = (__bf16*)((char*)d_ws + OFF_KB);
    __bf16* Vtb = (__bf16*)((char*)d_ws + OFF_VT);

    cvt_kernel<<<QK_ELEMS / 2048, 256, 0, stream>>>(q, Qb, SCALE);
    cvt_kernel<<<QK_ELEMS / 2048, 256, 0, stream>>>(k, Kb, 1.0f);
    vt_kernel<<<dim3(64, 4, 16), 256, 0, stream>>>(v, Vtb);

    attn2_kernel<<<dim3(16, 16), 256, 0, stream>>>(Qb, Kb, Vtb,
        lq1, lk1, lq2, lk2, out, stats);
  } else {
    attn_fb_kernel<<<dim3(32, NH, 2), 256, 0, stream>>>(q, k, v,
        lq1, lk1, lq2, lk2, out, stats);
  }

  const int total = 2 * NH * SEQ * DH;
  norm_kernel<<<total / 1024, 256, 0, stream>>>(out, stats, gw, gb);
}

// Round 4
// 232.345 us; speedup vs baseline: 2.4113x; 1.1098x over previous
//
#include <hip/hip_runtime.h>
#include <hip/hip_bf16.h>
#include <cstddef>
#include <cstdint>

// ---------------------------------------------------------------------------
// Differential attention (PraxisAttention).
// Round 4: 512 blocks (one 64-row q-tile each) -> 2 blocks/CU = 2 waves/SIMD
// for latency overlap; Q fp32->bf16 convert inlined into attn (cvt-Q kernel
// dropped); K bf16 and V^T bf16 pre-passes kept; fixed-m ghostmax;
// global_load_lds double-buffered staging with XOR bank swizzle.
// ---------------------------------------------------------------------------

typedef __bf16 bf16x8 __attribute__((ext_vector_type(8)));
typedef __bf16 bf16x4 __attribute__((ext_vector_type(4)));
typedef float f32x4 __attribute__((ext_vector_type(4)));

constexpr int SEQ = 2048;
constexpr int DH  = 128;
constexpr int NH  = 8;
constexpr int NH2 = 16;
constexpr float SCALE = 0.088388347648318447f; // 1/sqrt(128)

// ws layout (bytes):
//   [0,256)        : stats (sum, sumsq) per (b,h)
//   [4096, +16MB)  : Kb  bf16               [b][h2][t][d]
//   [.., +8MB)     : Vtb bf16               [b][h][d][t]
constexpr size_t QK_ELEMS = (size_t)2 * NH2 * SEQ * DH;   // 8,388,608
constexpr size_t V_ELEMS  = (size_t)2 * NH  * SEQ * DH;   // 4,194,304
constexpr size_t OFF_KB   = 4096;
constexpr size_t OFF_VT   = OFF_KB + QK_ELEMS * 2;
constexpr size_t WS_NEED  = OFF_VT + V_ELEMS * 2;

__device__ __forceinline__ void load_lds16(const void* g, void* l) {
  __builtin_amdgcn_global_load_lds(
      (const __attribute__((address_space(1))) uint32_t*)g,
      (__attribute__((address_space(3))) uint32_t*)l, 16, 0, 0);
}

__device__ __forceinline__ bf16x8 cvt8(float4 a, float4 b) {
  bf16x8 r;
  r[0] = (__bf16)a.x; r[1] = (__bf16)a.y; r[2] = (__bf16)a.z; r[3] = (__bf16)a.w;
  r[4] = (__bf16)b.x; r[5] = (__bf16)b.y; r[6] = (__bf16)b.z; r[7] = (__bf16)b.w;
  return r;
}

// ---------------- pre-pass: K -> bf16 --------------------------------------
__global__ __launch_bounds__(256) void cvt_kernel(
    const float* __restrict__ in, __bf16* __restrict__ out)
{
  const size_t i = ((size_t)blockIdx.x * 256 + threadIdx.x) * 8;
  float4 a = *(const float4*)(in + i);
  float4 b = *(const float4*)(in + i + 4);
  *(bf16x8*)(out + i) = cvt8(a, b);
}

// ---------------- pre-pass: V -> V^T (bf16) --------------------------------
__global__ __launch_bounds__(256) void vt_kernel(
    const float* __restrict__ v, __bf16* __restrict__ vt)
{
  __shared__ float tile[32][33];
  const int tt = blockIdx.x, dt = blockIdx.y, bh = blockIdx.z;
  const int tr = threadIdx.x >> 3, tc = (threadIdx.x & 7) * 4;
  const float* src = v + ((size_t)bh * SEQ + tt * 32) * DH + dt * 32;
  float4 f = *(const float4*)(src + (size_t)tr * DH + tc);
  tile[tr][tc + 0] = f.x; tile[tr][tc + 1] = f.y;
  tile[tr][tc + 2] = f.z; tile[tr][tc + 3] = f.w;
  __syncthreads();
  __bf16* dst = vt + ((size_t)bh * DH + dt * 32 + tr) * SEQ + tt * 32 + tc;
  bf16x4 o;
  o[0] = (__bf16)tile[tc + 0][tr];
  o[1] = (__bf16)tile[tc + 1][tr];
  o[2] = (__bf16)tile[tc + 2][tr];
  o[3] = (__bf16)tile[tc + 3][tr];
  *(bf16x4*)dst = o;
}

// ---------------- main attention kernel ------------------------------------
__global__ __launch_bounds__(256, 2) void attn2_kernel(
    const float* __restrict__ Qf, const __bf16* __restrict__ Kb,
    const __bf16* __restrict__ Vtb,
    const float* __restrict__ lq1, const float* __restrict__ lk1,
    const float* __restrict__ lq2, const float* __restrict__ lk2,
    float* __restrict__ Obuf, float* __restrict__ stats)
{
  // packed (no pad) for global_load_lds; XOR-swizzled chunk placement
  __shared__ __align__(16) __bf16 ldsK[2][2][32][128];  // [buf][sh][kr][d] 16KB/buf
  __shared__ __align__(16) __bf16 ldsVt[2][128][32];    // [buf][d][t]      8KB/buf
  __shared__ __align__(16) __bf16 ldsP[4][2][16][40];   // [wave][sh][r][t] pad40

  const int qt = 31 - blockIdx.x;  // large tiles dispatch first
  const int bh = blockIdx.y;       // 0..15
  const int b = bh >> 3, h = bh & 7;
  const int tid = threadIdx.x;
  const int w = tid >> 6, lane = tid & 63;
  const int l15 = lane & 15, quad = lane >> 4;

  // ---- lambda scalar ----
  float a1 = lq1[lane]*lk1[lane] + lq1[lane+64]*lk1[lane+64];
  float a2 = lq2[lane]*lk2[lane] + lq2[lane+64]*lk2[lane+64];
  #pragma unroll
  for (int off = 1; off < 64; off <<= 1) {
    a1 += __shfl_xor(a1, off);
    a2 += __shfl_xor(a2, off);
  }
  const float lam = __expf(a1) - __expf(a2) + 0.8f;

  const size_t headQK = (size_t)(b*NH2 + 2*h) * SEQ * DH;
  const float*  Qh  = Qf + headQK;
  const __bf16* Kh  = Kb + headQK;
  const __bf16* Vth = Vtb + (size_t)(b*NH + h) * DH * SEQ;

  // ---- per-lane staging source offsets (element units, swizzled) ----
  size_t goffK[4];
  #pragma unroll
  for (int i = 0; i < 4; ++i) {
    const int R  = w*16 + i*4 + quad;      // flat row 0..63
    const int sh = R >> 5, kr = R & 31;
    const int cs = lane & 15;              // LDS chunk slot
    goffK[i] = ((size_t)sh * SEQ + kr) * DH + ((cs ^ (kr & 15)) * 8);
  }
  size_t goffV[2];
  #pragma unroll
  for (int i = 0; i < 2; ++i) {
    const int d  = w*32 + i*16 + (lane >> 2);
    const int cs = lane & 3;
    goffV[i] = (size_t)d * SEQ + ((cs ^ (d & 3)) * 8);
  }

  __bf16* ldsKb0 = &ldsK[0][0][0][0];
  __bf16* ldsVb0 = &ldsVt[0][0][0];

  const int qb = qt * 64, nsteps = 2 * (qt + 1);

  // Q fragments: fp32 global -> scale -> bf16 A-layout (read once per block)
  const int qrow = qb + w*16 + l15;
  bf16x8 qf[2][4];
  #pragma unroll
  for (int sh = 0; sh < 2; ++sh) {
    const float* src = Qh + (size_t)sh*SEQ*DH + (size_t)qrow*DH + quad*8;
    #pragma unroll
    for (int kd = 0; kd < 4; ++kd) {
      float4 f0 = *(const float4*)(src + kd*32);
      float4 f1 = *(const float4*)(src + kd*32 + 4);
      f0.x *= SCALE; f0.y *= SCALE; f0.z *= SCALE; f0.w *= SCALE;
      f1.x *= SCALE; f1.y *= SCALE; f1.z *= SCALE; f1.w *= SCALE;
      qf[sh][kd] = cvt8(f0, f1);
    }
  }

  f32x4 oacc[2][8];
  float lsum[2][4];
  #pragma unroll
  for (int sh = 0; sh < 2; ++sh) {
    #pragma unroll
    for (int nt = 0; nt < 8; ++nt) oacc[sh][nt] = (f32x4){0.f,0.f,0.f,0.f};
    #pragma unroll
    for (int r = 0; r < 4; ++r) lsum[sh][r] = 0.f;
  }

  // stage step 0 into buf 0
  {
    const __bf16* kg = Kh;
    #pragma unroll
    for (int i = 0; i < 4; ++i)
      load_lds16(kg + goffK[i], ldsKb0 + w*2048 + i*512);
    const __bf16* vg = Vth;
    #pragma unroll
    for (int i = 0; i < 2; ++i)
      load_lds16(vg + goffV[i], ldsVb0 + w*1024 + i*512);
  }
  __syncthreads();

  for (int st = 0; st < nsteps; ++st) {
    const int cur = st & 1;
    const int kbt = st * 32;

    // async prefetch next tile into the other buffer
    if (st + 1 < nsteps) {
      const int nxt = cur ^ 1;
      const __bf16* kg = Kh + (size_t)(kbt + 32) * DH;
      #pragma unroll
      for (int i = 0; i < 4; ++i)
        load_lds16(kg + goffK[i], ldsKb0 + (size_t)nxt*8192 + w*2048 + i*512);
      const __bf16* vg = Vth + (kbt + 32);
      #pragma unroll
      for (int i = 0; i < 2; ++i)
        load_lds16(vg + goffV[i], ldsVb0 + (size_t)nxt*4096 + w*1024 + i*512);
    }

    // ---- S = Q K^T ----
    f32x4 sacc[2][2];
    #pragma unroll
    for (int sh = 0; sh < 2; ++sh)
      #pragma unroll
      for (int n = 0; n < 2; ++n)
        sacc[sh][n] = (f32x4){0.f,0.f,0.f,0.f};
    #pragma unroll
    for (int sh = 0; sh < 2; ++sh)
      #pragma unroll
      for (int n = 0; n < 2; ++n)
        #pragma unroll
        for (int kd = 0; kd < 4; ++kd) {
          bf16x8 kf = *(const bf16x8*)&ldsK[cur][sh][n*16 + l15][((kd*4 + quad) ^ l15) * 8];
          sacc[sh][n] = __builtin_amdgcn_mfma_f32_16x16x32_bf16(qf[sh][kd], kf, sacc[sh][n], 0, 0, 0);
        }

    // ---- fixed-m ghostmax: p = exp(s) (masked), accumulate l per-lane ----
    const int qrow0 = qb + w*16 + quad*4;
    #pragma unroll
    for (int sh = 0; sh < 2; ++sh)
      #pragma unroll
      for (int r = 0; r < 4; ++r) {
        const int qr = qrow0 + r;
        const float p0 = (kbt + l15      <= qr) ? __expf(sacc[sh][0][r]) : 0.f;
        const float p1 = (kbt + l15 + 16 <= qr) ? __expf(sacc[sh][1][r]) : 0.f;
        lsum[sh][r] += p0 + p1;
        ldsP[w][sh][quad*4 + r][l15]      = (__bf16)p0;
        ldsP[w][sh][quad*4 + r][l15 + 16] = (__bf16)p1;
      }

    // ---- O += P V ----
    {
      bf16x8 pf0 = *(const bf16x8*)&ldsP[w][0][l15][quad*8];
      bf16x8 pf1 = *(const bf16x8*)&ldsP[w][1][l15][quad*8];
      #pragma unroll
      for (int nt = 0; nt < 8; ++nt) {
        bf16x8 vf = *(const bf16x8*)&ldsVt[cur][nt*16 + l15][(quad ^ (l15 & 3)) * 8];
        oacc[0][nt] = __builtin_amdgcn_mfma_f32_16x16x32_bf16(pf0, vf, oacc[0][nt], 0, 0, 0);
        oacc[1][nt] = __builtin_amdgcn_mfma_f32_16x16x32_bf16(pf1, vf, oacc[1][nt], 0, 0, 0);
      }
    }
    __syncthreads();
  }

  // ---- epilogue ----
  #pragma unroll
  for (int sh = 0; sh < 2; ++sh)
    #pragma unroll
    for (int r = 0; r < 4; ++r) {
      float vsum = lsum[sh][r];
      #pragma unroll
      for (int off = 1; off < 16; off <<= 1) vsum += __shfl_xor(vsum, off);
      lsum[sh][r] = vsum + 1.0f;   // ghost logit
    }

  const int qrow0 = qb + w*16 + quad*4;
  float* obase = Obuf + (size_t)(b*NH + h) * SEQ * DH;
  float sum = 0.f, ss = 0.f;
  #pragma unroll
  for (int r = 0; r < 4; ++r) {
    const float i0 = 1.0f / lsum[0][r];
    const float i1 = lam / lsum[1][r];
    float* orow = obase + (size_t)(qrow0 + r) * DH + l15;
    #pragma unroll
    for (int nt = 0; nt < 8; ++nt) {
      const float val = oacc[0][nt][r] * i0 - oacc[1][nt][r] * i1;
      orow[nt*16] = val;
      sum += val;
      ss  += val * val;
    }
  }
  #pragma unroll
  for (int off = 1; off < 64; off <<= 1) {
    sum += __shfl_xor(sum, off);
    ss  += __shfl_xor(ss, off);
  }
  if (lane == 0) {
    atomicAdd(&stats[2*(b*NH + h)],     sum);
    atomicAdd(&stats[2*(b*NH + h) + 1], ss);
  }
}

// ---------------- fallback (round-1) attention kernel ----------------------
__global__ __launch_bounds__(256) void attn_fb_kernel(
    const float* __restrict__ q, const float* __restrict__ k,
    const float* __restrict__ v,
    const float* __restrict__ lq1, const float* __restrict__ lk1,
    const float* __restrict__ lq2, const float* __restrict__ lk2,
    float* __restrict__ Obuf, float* __restrict__ stats)
{
  __shared__ __align__(16) __bf16 lds_k[2][32][136];
  __shared__ __align__(16) __bf16 lds_vt[128][40];
  __shared__ __align__(16) __bf16 lds_p[4][2][16][40];

  const int qt = blockIdx.x, h = blockIdx.y, b = blockIdx.z;
  const int qb = qt * 64;
  const int tid = threadIdx.x;
  const int w = tid >> 6, lane = tid & 63;
  const int l15 = lane & 15, quad = lane >> 4;

  float a1 = lq1[lane]*lk1[lane] + lq1[lane+64]*lk1[lane+64];
  float a2 = lq2[lane]*lk2[lane] + lq2[lane+64]*lk2[lane+64];
  #pragma unroll
  for (int off = 1; off < 64; off <<= 1) {
    a1 += __shfl_xor(a1, off);
    a2 += __shfl_xor(a2, off);
  }
  const float lam = __expf(a1) - __expf(a2) + 0.8f;

  const float* qh0 = q + (size_t)(b*NH2 + 2*h) * SEQ * DH;
  const float* qh1 = qh0 + (size_t)SEQ * DH;
  const float* kh0 = k + (size_t)(b*NH2 + 2*h) * SEQ * DH;
  const float* kh1 = kh0 + (size_t)SEQ * DH;
  const float* vh  = v + (size_t)(b*NH + h) * SEQ * DH;

  bf16x8 qf[2][4];
  {
    const int qrow = qb + w*16 + l15;
    #pragma unroll
    for (int sh = 0; sh < 2; ++sh) {
      const float* src = (sh ? qh1 : qh0) + (size_t)qrow * DH + quad*8;
      #pragma unroll
      for (int kd = 0; kd < 4; ++kd) {
        float4 f0 = *(const float4*)(src + kd*32);
        float4 f1 = *(const float4*)(src + kd*32 + 4);
        qf[sh][kd] = cvt8(f0, f1);
      }
    }
  }

  f32x4 oacc[2][8];
  #pragma unroll
  for (int sh = 0; sh < 2; ++sh)
    #pragma unroll
    for (int nt = 0; nt < 8; ++nt)
      oacc[sh][nt] = (f32x4){0.f,0.f,0.f,0.f};

  float mst[2][4] = {{0.f,0.f,0.f,0.f},{0.f,0.f,0.f,0.f}};
  float lst[2][4] = {{1.f,1.f,1.f,1.f},{1.f,1.f,1.f,1.f}};

  const int krow = tid >> 2, ksh = krow >> 5, kr = krow & 31;
  const int kd0 = (tid & 3) * 32;
  const float* ksrc0 = (ksh ? kh1 : kh0) + kd0;
  const int vt = tid >> 3, vd = (tid & 7) * 16;

  const int nsteps = (qb + 64) / 32;
  for (int st = 0; st < nsteps; ++st) {
    const int kbt = st * 32;
    {
      const float* sp = ksrc0 + (size_t)(kbt + kr) * DH;
      #pragma unroll
      for (int c = 0; c < 4; ++c) {
        float4 f0 = *(const float4*)(sp + c*8);
        float4 f1 = *(const float4*)(sp + c*8 + 4);
        *(bf16x8*)&lds_k[ksh][kr][kd0 + c*8] = cvt8(f0, f1);
      }
      const float* vp = vh + (size_t)(kbt + vt) * DH + vd;
      #pragma unroll
      for (int c = 0; c < 4; ++c) {
        float4 f = *(const float4*)(vp + c*4);
        lds_vt[vd + c*4 + 0][vt] = (__bf16)f.x;
        lds_vt[vd + c*4 + 1][vt] = (__bf16)f.y;
        lds_vt[vd + c*4 + 2][vt] = (__bf16)f.z;
        lds_vt[vd + c*4 + 3][vt] = (__bf16)f.w;
      }
    }
    __syncthreads();

    f32x4 sacc[2][2];
    #pragma unroll
    for (int sh = 0; sh < 2; ++sh)
      #pragma unroll
      for (int n = 0; n < 2; ++n)
        sacc[sh][n] = (f32x4){0.f,0.f,0.f,0.f};

    #pragma unroll
    for (int sh = 0; sh < 2; ++sh)
      #pragma unroll
      for (int n = 0; n < 2; ++n)
        #pragma unroll
        for (int kd = 0; kd < 4; ++kd) {
          bf16x8 bf = *(const bf16x8*)&lds_k[sh][n*16 + l15][kd*32 + quad*8];
          sacc[sh][n] = __builtin_amdgcn_mfma_f32_16x16x32_bf16(qf[sh][kd], bf, sacc[sh][n], 0, 0, 0);
        }

    const int qrow0 = qb + w*16 + quad*4;
    const int c0 = kbt + l15, c1 = c0 + 16;
    #pragma unroll
    for (int sh = 0; sh < 2; ++sh) {
      #pragma unroll
      for (int r = 0; r < 4; ++r) {
        float s0 = sacc[sh][0][r] * SCALE;
        float s1 = sacc[sh][1][r] * SCALE;
        const int qr = qrow0 + r;
        if (c0 > qr) s0 = -1e30f;
        if (c1 > qr) s1 = -1e30f;
        float mx = fmaxf(s0, s1);
        #pragma unroll
        for (int off = 1; off < 16; off <<= 1)
          mx = fmaxf(mx, __shfl_xor(mx, off));
        const float mnew = fmaxf(mst[sh][r], mx);
        const float alpha = __expf(mst[sh][r] - mnew);
        mst[sh][r] = mnew;
        const float p0 = __expf(s0 - mnew);
        const float p1 = __expf(s1 - mnew);
        float rs = p0 + p1;
        #pragma unroll
        for (int off = 1; off < 16; off <<= 1)
          rs += __shfl_xor(rs, off);
        lst[sh][r] = lst[sh][r] * alpha + rs;
        #pragma unroll
        for (int nt = 0; nt < 8; ++nt)
          oacc[sh][nt][r] *= alpha;
        lds_p[w][sh][quad*4 + r][l15]      = (__bf16)p0;
        lds_p[w][sh][quad*4 + r][l15 + 16] = (__bf16)p1;
      }
    }

    {
      bf16x8 pf0 = *(const bf16x8*)&lds_p[w][0][l15][quad*8];
      bf16x8 pf1 = *(const bf16x8*)&lds_p[w][1][l15][quad*8];
      #pragma unroll
      for (int nt = 0; nt < 8; ++nt) {
        bf16x8 vf = *(const bf16x8*)&lds_vt[nt*16 + l15][quad*8];
        oacc[0][nt] = __builtin_amdgcn_mfma_f32_16x16x32_bf16(pf0, vf, oacc[0][nt], 0, 0, 0);
        oacc[1][nt] = __builtin_amdgcn_mfma_f32_16x16x32_bf16(pf1, vf, oacc[1][nt], 0, 0, 0);
      }
    }
    __syncthreads();
  }

  const int qrow0 = qb + w*16 + quad*4;
  float* obase = Obuf + (size_t)(b*NH + h) * SEQ * DH;
  float sum = 0.f, ss = 0.f;
  #pragma unroll
  for (int r = 0; r < 4; ++r) {
    const float i0 = 1.0f / lst[0][r];
    const float i1 = lam / lst[1][r];
    float* orow = obase + (size_t)(qrow0 + r) * DH + l15;
    #pragma unroll
    for (int nt = 0; nt < 8; ++nt) {
      const float val = oacc[0][nt][r] * i0 - oacc[1][nt][r] * i1;
      orow[nt*16] = val;
      sum += val;
      ss  += val * val;
    }
  }
  #pragma unroll
  for (int off = 1; off < 64; off <<= 1) {
    sum += __shfl_xor(sum, off);
    ss  += __shfl_xor(ss, off);
  }
  if (lane == 0) {
    atomicAdd(&stats[2*(b*NH + h)],     sum);
    atomicAdd(&stats[2*(b*NH + h) + 1], ss);
  }
}

// ---------------- GroupNorm epilogue ---------------------------------------
__global__ __launch_bounds__(256) void norm_kernel(
    float* __restrict__ Obuf, const float* __restrict__ stats,
    const float* __restrict__ gw, const float* __restrict__ gb)
{
  const int idx = (blockIdx.x * 256 + threadIdx.x) * 4;
  const int bh = idx >> 18;
  const int local = idx & 262143;
  const float inv = 1.0f / 262144.0f;
  const float mean = stats[2*bh] * inv;
  const float var  = stats[2*bh + 1] * inv - mean * mean;
  const float rstd = rsqrtf(var + 1e-5f);
  const int c = ((bh & 7) << 7) + (local >> 11);
  const float wq = gw[c] * rstd;
  const float bq = gb[c];
  float4 o = *(const float4*)(Obuf + idx);
  float4 r;
  r.x = ((o.x - mean) * wq + bq) * 0.2f;
  r.y = ((o.y - mean) * wq + bq) * 0.2f;
  r.z = ((o.z - mean) * wq + bq) * 0.2f;
  r.w = ((o.w - mean) * wq + bq) * 0.2f;
  *(float4*)(Obuf + idx) = r;
}

extern "C" void kernel_launch(void* const* d_in, const int* in_sizes, int n_in,
                              void* d_out, int out_size, void* d_ws, size_t ws_size,
                              hipStream_t stream) {
  const float* q   = (const float*)d_in[0];
  const float* k   = (const float*)d_in[1];
  const float* v   = (const float*)d_in[2];
  const float* lq1 = (const float*)d_in[3];
  const float* lk1 = (const float*)d_in[4];
  const float* lq2 = (const float*)d_in[5];
  const float* lk2 = (const float*)d_in[6];
  const float* gw  = (const float*)d_in[7];
  const float* gb  = (const float*)d_in[8];
  float* out = (float*)d_out;
  float* stats = (float*)d_ws;

  (void)hipMemsetAsync(d_ws, 0, 256, stream);

  if (ws_size >= WS_NEED) {
    __bf16* Kb  = (__bf16*)((char*)d_ws + OFF_KB);
    __bf16* Vtb = (__bf16*)((char*)d_ws + OFF_VT);

    cvt_kernel<<<QK_ELEMS / 2048, 256, 0, stream>>>(k, Kb);
    vt_kernel<<<dim3(64, 4, 16), 256, 0, stream>>>(v, Vtb);

    attn2_kernel<<<dim3(32, 16), 256, 0, stream>>>(q, Kb, Vtb,
        lq1, lk1, lq2, lk2, out, stats);
  } else {
    attn_fb_kernel<<<dim3(32, NH, 2), 256, 0, stream>>>(q, k, v,
        lq1, lk1, lq2, lk2, out, stats);
  }

  const int total = 2 * NH * SEQ * DH;
  norm_kernel<<<total / 1024, 256, 0, stream>>>(out, stats, gw, gb);
}

// Round 5
// 216.545 us; speedup vs baseline: 2.5873x; 1.0730x over previous
//
#include <hip/hip_runtime.h>
#include <hip/hip_bf16.h>
#include <cstddef>
#include <cstdint>

// ---------------------------------------------------------------------------
// Differential attention (PraxisAttention).
// Round 5: complementary qt remap so the two co-resident blocks per CU have
// qt summing to 31 (uniform 68 steps/CU); prep fused into one kernel
// (K->bf16, V->V^T bf16, stats zero) -> 3 dispatches total.
// ---------------------------------------------------------------------------

typedef __bf16 bf16x8 __attribute__((ext_vector_type(8)));
typedef __bf16 bf16x4 __attribute__((ext_vector_type(4)));
typedef float f32x4 __attribute__((ext_vector_type(4)));

constexpr int SEQ = 2048;
constexpr int DH  = 128;
constexpr int NH  = 8;
constexpr int NH2 = 16;
constexpr float SCALE = 0.088388347648318447f; // 1/sqrt(128)

// ws layout (bytes):
//   [0,256)        : stats (sum, sumsq) per (b,h)
//   [4096, +16MB)  : Kb  bf16               [b][h2][t][d]
//   [.., +8MB)     : Vtb bf16               [b][h][d][t]
constexpr size_t QK_ELEMS = (size_t)2 * NH2 * SEQ * DH;   // 8,388,608
constexpr size_t V_ELEMS  = (size_t)2 * NH  * SEQ * DH;   // 4,194,304
constexpr size_t OFF_KB   = 4096;
constexpr size_t OFF_VT   = OFF_KB + QK_ELEMS * 2;
constexpr size_t WS_NEED  = OFF_VT + V_ELEMS * 2;

__device__ __forceinline__ void load_lds16(const void* g, void* l) {
  __builtin_amdgcn_global_load_lds(
      (const __attribute__((address_space(1))) uint32_t*)g,
      (__attribute__((address_space(3))) uint32_t*)l, 16, 0, 0);
}

__device__ __forceinline__ bf16x8 cvt8(float4 a, float4 b) {
  bf16x8 r;
  r[0] = (__bf16)a.x; r[1] = (__bf16)a.y; r[2] = (__bf16)a.z; r[3] = (__bf16)a.w;
  r[4] = (__bf16)b.x; r[5] = (__bf16)b.y; r[6] = (__bf16)b.z; r[7] = (__bf16)b.w;
  return r;
}

// ---------------- fused pre-pass: K->bf16, V->V^T bf16, stats zero ---------
__global__ __launch_bounds__(256) void prep_kernel(
    const float* __restrict__ k, const float* __restrict__ v,
    __bf16* __restrict__ Kb, __bf16* __restrict__ Vtb,
    float* __restrict__ stats)
{
  __shared__ float tile[32][33];
  const int id = blockIdx.x;
  if (id == 0 && threadIdx.x < 64) stats[threadIdx.x] = 0.f;
  if (id < 4096) {
    // K convert: 2048 elems per block
    const size_t i = ((size_t)id * 256 + threadIdx.x) * 8;
    float4 a = *(const float4*)(k + i);
    float4 b = *(const float4*)(k + i + 4);
    *(bf16x8*)(Kb + i) = cvt8(a, b);
  } else {
    // V transpose: 32x32 tile
    const int vid = id - 4096;
    const int tt = vid & 63, dt = (vid >> 6) & 3, bh = vid >> 8;
    const int tr = threadIdx.x >> 3, tc = (threadIdx.x & 7) * 4;
    const float* src = v + ((size_t)bh * SEQ + tt * 32) * DH + dt * 32;
    float4 f = *(const float4*)(src + (size_t)tr * DH + tc);
    tile[tr][tc + 0] = f.x; tile[tr][tc + 1] = f.y;
    tile[tr][tc + 2] = f.z; tile[tr][tc + 3] = f.w;
    __syncthreads();
    __bf16* dst = Vtb + ((size_t)bh * DH + dt * 32 + tr) * SEQ + tt * 32 + tc;
    bf16x4 o;
    o[0] = (__bf16)tile[tc + 0][tr];
    o[1] = (__bf16)tile[tc + 1][tr];
    o[2] = (__bf16)tile[tc + 2][tr];
    o[3] = (__bf16)tile[tc + 3][tr];
    *(bf16x4*)dst = o;
  }
}

// ---------------- main attention kernel ------------------------------------
__global__ __launch_bounds__(256, 2) void attn2_kernel(
    const float* __restrict__ Qf, const __bf16* __restrict__ Kb,
    const __bf16* __restrict__ Vtb,
    const float* __restrict__ lq1, const float* __restrict__ lk1,
    const float* __restrict__ lq2, const float* __restrict__ lk2,
    float* __restrict__ Obuf, float* __restrict__ stats)
{
  // packed (no pad) for global_load_lds; XOR-swizzled chunk placement
  __shared__ __align__(16) __bf16 ldsK[2][2][32][128];  // [buf][sh][kr][d] 16KB/buf
  __shared__ __align__(16) __bf16 ldsVt[2][128][32];    // [buf][d][t]      8KB/buf
  __shared__ __align__(16) __bf16 ldsP[4][2][16][40];   // [wave][sh][r][t] pad40

  // complementary remap: blocks L and L+256 (same CU slot pair) have
  // qt summing to 31 -> uniform 68 steps per CU.
  const int qt = (blockIdx.y < 8) ? (31 - (int)blockIdx.x) : (int)blockIdx.x;
  const int bh = blockIdx.y;       // 0..15
  const int b = bh >> 3, h = bh & 7;
  const int tid = threadIdx.x;
  const int w = tid >> 6, lane = tid & 63;
  const int l15 = lane & 15, quad = lane >> 4;

  // ---- lambda scalar ----
  float a1 = lq1[lane]*lk1[lane] + lq1[lane+64]*lk1[lane+64];
  float a2 = lq2[lane]*lk2[lane] + lq2[lane+64]*lk2[lane+64];
  #pragma unroll
  for (int off = 1; off < 64; off <<= 1) {
    a1 += __shfl_xor(a1, off);
    a2 += __shfl_xor(a2, off);
  }
  const float lam = __expf(a1) - __expf(a2) + 0.8f;

  const size_t headQK = (size_t)(b*NH2 + 2*h) * SEQ * DH;
  const float*  Qh  = Qf + headQK;
  const __bf16* Kh  = Kb + headQK;
  const __bf16* Vth = Vtb + (size_t)(b*NH + h) * DH * SEQ;

  // ---- per-lane staging source offsets (element units, swizzled) ----
  size_t goffK[4];
  #pragma unroll
  for (int i = 0; i < 4; ++i) {
    const int R  = w*16 + i*4 + quad;      // flat row 0..63
    const int sh = R >> 5, kr = R & 31;
    const int cs = lane & 15;              // LDS chunk slot
    goffK[i] = ((size_t)sh * SEQ + kr) * DH + ((cs ^ (kr & 15)) * 8);
  }
  size_t goffV[2];
  #pragma unroll
  for (int i = 0; i < 2; ++i) {
    const int d  = w*32 + i*16 + (lane >> 2);
    const int cs = lane & 3;
    goffV[i] = (size_t)d * SEQ + ((cs ^ (d & 3)) * 8);
  }

  __bf16* ldsKb0 = &ldsK[0][0][0][0];
  __bf16* ldsVb0 = &ldsVt[0][0][0];

  const int qb = qt * 64, nsteps = 2 * (qt + 1);

  // Q fragments: fp32 global -> scale -> bf16 A-layout (read once per block)
  const int qrow = qb + w*16 + l15;
  bf16x8 qf[2][4];
  #pragma unroll
  for (int sh = 0; sh < 2; ++sh) {
    const float* src = Qh + (size_t)sh*SEQ*DH + (size_t)qrow*DH + quad*8;
    #pragma unroll
    for (int kd = 0; kd < 4; ++kd) {
      float4 f0 = *(const float4*)(src + kd*32);
      float4 f1 = *(const float4*)(src + kd*32 + 4);
      f0.x *= SCALE; f0.y *= SCALE; f0.z *= SCALE; f0.w *= SCALE;
      f1.x *= SCALE; f1.y *= SCALE; f1.z *= SCALE; f1.w *= SCALE;
      qf[sh][kd] = cvt8(f0, f1);
    }
  }

  f32x4 oacc[2][8];
  float lsum[2][4];
  #pragma unroll
  for (int sh = 0; sh < 2; ++sh) {
    #pragma unroll
    for (int nt = 0; nt < 8; ++nt) oacc[sh][nt] = (f32x4){0.f,0.f,0.f,0.f};
    #pragma unroll
    for (int r = 0; r < 4; ++r) lsum[sh][r] = 0.f;
  }

  // stage step 0 into buf 0
  {
    const __bf16* kg = Kh;
    #pragma unroll
    for (int i = 0; i < 4; ++i)
      load_lds16(kg + goffK[i], ldsKb0 + w*2048 + i*512);
    const __bf16* vg = Vth;
    #pragma unroll
    for (int i = 0; i < 2; ++i)
      load_lds16(vg + goffV[i], ldsVb0 + w*1024 + i*512);
  }
  __syncthreads();

  for (int st = 0; st < nsteps; ++st) {
    const int cur = st & 1;
    const int kbt = st * 32;

    // async prefetch next tile into the other buffer
    if (st + 1 < nsteps) {
      const int nxt = cur ^ 1;
      const __bf16* kg = Kh + (size_t)(kbt + 32) * DH;
      #pragma unroll
      for (int i = 0; i < 4; ++i)
        load_lds16(kg + goffK[i], ldsKb0 + (size_t)nxt*8192 + w*2048 + i*512);
      const __bf16* vg = Vth + (kbt + 32);
      #pragma unroll
      for (int i = 0; i < 2; ++i)
        load_lds16(vg + goffV[i], ldsVb0 + (size_t)nxt*4096 + w*1024 + i*512);
    }

    // ---- S = Q K^T ----
    f32x4 sacc[2][2];
    #pragma unroll
    for (int sh = 0; sh < 2; ++sh)
      #pragma unroll
      for (int n = 0; n < 2; ++n)
        sacc[sh][n] = (f32x4){0.f,0.f,0.f,0.f};
    #pragma unroll
    for (int sh = 0; sh < 2; ++sh)
      #pragma unroll
      for (int n = 0; n < 2; ++n)
        #pragma unroll
        for (int kd = 0; kd < 4; ++kd) {
          bf16x8 kf = *(const bf16x8*)&ldsK[cur][sh][n*16 + l15][((kd*4 + quad) ^ l15) * 8];
          sacc[sh][n] = __builtin_amdgcn_mfma_f32_16x16x32_bf16(qf[sh][kd], kf, sacc[sh][n], 0, 0, 0);
        }

    // ---- fixed-m ghostmax: p = exp(s) (masked), accumulate l per-lane ----
    const int qrow0 = qb + w*16 + quad*4;
    #pragma unroll
    for (int sh = 0; sh < 2; ++sh)
      #pragma unroll
      for (int r = 0; r < 4; ++r) {
        const int qr = qrow0 + r;
        const float p0 = (kbt + l15      <= qr) ? __expf(sacc[sh][0][r]) : 0.f;
        const float p1 = (kbt + l15 + 16 <= qr) ? __expf(sacc[sh][1][r]) : 0.f;
        lsum[sh][r] += p0 + p1;
        ldsP[w][sh][quad*4 + r][l15]      = (__bf16)p0;
        ldsP[w][sh][quad*4 + r][l15 + 16] = (__bf16)p1;
      }

    // ---- O += P V ----
    {
      bf16x8 pf0 = *(const bf16x8*)&ldsP[w][0][l15][quad*8];
      bf16x8 pf1 = *(const bf16x8*)&ldsP[w][1][l15][quad*8];
      #pragma unroll
      for (int nt = 0; nt < 8; ++nt) {
        bf16x8 vf = *(const bf16x8*)&ldsVt[cur][nt*16 + l15][(quad ^ (l15 & 3)) * 8];
        oacc[0][nt] = __builtin_amdgcn_mfma_f32_16x16x32_bf16(pf0, vf, oacc[0][nt], 0, 0, 0);
        oacc[1][nt] = __builtin_amdgcn_mfma_f32_16x16x32_bf16(pf1, vf, oacc[1][nt], 0, 0, 0);
      }
    }
    __syncthreads();
  }

  // ---- epilogue ----
  #pragma unroll
  for (int sh = 0; sh < 2; ++sh)
    #pragma unroll
    for (int r = 0; r < 4; ++r) {
      float vsum = lsum[sh][r];
      #pragma unroll
      for (int off = 1; off < 16; off <<= 1) vsum += __shfl_xor(vsum, off);
      lsum[sh][r] = vsum + 1.0f;   // ghost logit
    }

  const int qrow0 = qb + w*16 + quad*4;
  float* obase = Obuf + (size_t)(b*NH + h) * SEQ * DH;
  float sum = 0.f, ss = 0.f;
  #pragma unroll
  for (int r = 0; r < 4; ++r) {
    const float i0 = 1.0f / lsum[0][r];
    const float i1 = lam / lsum[1][r];
    float* orow = obase + (size_t)(qrow0 + r) * DH + l15;
    #pragma unroll
    for (int nt = 0; nt < 8; ++nt) {
      const float val = oacc[0][nt][r] * i0 - oacc[1][nt][r] * i1;
      orow[nt*16] = val;
      sum += val;
      ss  += val * val;
    }
  }
  #pragma unroll
  for (int off = 1; off < 64; off <<= 1) {
    sum += __shfl_xor(sum, off);
    ss  += __shfl_xor(ss, off);
  }
  if (lane == 0) {
    atomicAdd(&stats[2*(b*NH + h)],     sum);
    atomicAdd(&stats[2*(b*NH + h) + 1], ss);
  }
}

// ---------------- fallback (round-1) attention kernel ----------------------
__global__ __launch_bounds__(256) void attn_fb_kernel(
    const float* __restrict__ q, const float* __restrict__ k,
    const float* __restrict__ v,
    const float* __restrict__ lq1, const float* __restrict__ lk1,
    const float* __restrict__ lq2, const float* __restrict__ lk2,
    float* __restrict__ Obuf, float* __restrict__ stats)
{
  __shared__ __align__(16) __bf16 lds_k[2][32][136];
  __shared__ __align__(16) __bf16 lds_vt[128][40];
  __shared__ __align__(16) __bf16 lds_p[4][2][16][40];

  const int qt = blockIdx.x, h = blockIdx.y, b = blockIdx.z;
  const int qb = qt * 64;
  const int tid = threadIdx.x;
  const int w = tid >> 6, lane = tid & 63;
  const int l15 = lane & 15, quad = lane >> 4;

  float a1 = lq1[lane]*lk1[lane] + lq1[lane+64]*lk1[lane+64];
  float a2 = lq2[lane]*lk2[lane] + lq2[lane+64]*lk2[lane+64];
  #pragma unroll
  for (int off = 1; off < 64; off <<= 1) {
    a1 += __shfl_xor(a1, off);
    a2 += __shfl_xor(a2, off);
  }
  const float lam = __expf(a1) - __expf(a2) + 0.8f;

  const float* qh0 = q + (size_t)(b*NH2 + 2*h) * SEQ * DH;
  const float* qh1 = qh0 + (size_t)SEQ * DH;
  const float* kh0 = k + (size_t)(b*NH2 + 2*h) * SEQ * DH;
  const float* kh1 = kh0 + (size_t)SEQ * DH;
  const float* vh  = v + (size_t)(b*NH + h) * SEQ * DH;

  bf16x8 qf[2][4];
  {
    const int qrow = qb + w*16 + l15;
    #pragma unroll
    for (int sh = 0; sh < 2; ++sh) {
      const float* src = (sh ? qh1 : qh0) + (size_t)qrow * DH + quad*8;
      #pragma unroll
      for (int kd = 0; kd < 4; ++kd) {
        float4 f0 = *(const float4*)(src + kd*32);
        float4 f1 = *(const float4*)(src + kd*32 + 4);
        qf[sh][kd] = cvt8(f0, f1);
      }
    }
  }

  f32x4 oacc[2][8];
  #pragma unroll
  for (int sh = 0; sh < 2; ++sh)
    #pragma unroll
    for (int nt = 0; nt < 8; ++nt)
      oacc[sh][nt] = (f32x4){0.f,0.f,0.f,0.f};

  float mst[2][4] = {{0.f,0.f,0.f,0.f},{0.f,0.f,0.f,0.f}};
  float lst[2][4] = {{1.f,1.f,1.f,1.f},{1.f,1.f,1.f,1.f}};

  const int krow = tid >> 2, ksh = krow >> 5, kr = krow & 31;
  const int kd0 = (tid & 3) * 32;
  const float* ksrc0 = (ksh ? kh1 : kh0) + kd0;
  const int vt = tid >> 3, vd = (tid & 7) * 16;

  const int nsteps = (qb + 64) / 32;
  for (int st = 0; st < nsteps; ++st) {
    const int kbt = st * 32;
    {
      const float* sp = ksrc0 + (size_t)(kbt + kr) * DH;
      #pragma unroll
      for (int c = 0; c < 4; ++c) {
        float4 f0 = *(const float4*)(sp + c*8);
        float4 f1 = *(const float4*)(sp + c*8 + 4);
        *(bf16x8*)&lds_k[ksh][kr][kd0 + c*8] = cvt8(f0, f1);
      }
      const float* vp = vh + (size_t)(kbt + vt) * DH + vd;
      #pragma unroll
      for (int c = 0; c < 4; ++c) {
        float4 f = *(const float4*)(vp + c*4);
        lds_vt[vd + c*4 + 0][vt] = (__bf16)f.x;
        lds_vt[vd + c*4 + 1][vt] = (__bf16)f.y;
        lds_vt[vd + c*4 + 2][vt] = (__bf16)f.z;
        lds_vt[vd + c*4 + 3][vt] = (__bf16)f.w;
      }
    }
    __syncthreads();

    f32x4 sacc[2][2];
    #pragma unroll
    for (int sh = 0; sh < 2; ++sh)
      #pragma unroll
      for (int n = 0; n < 2; ++n)
        sacc[sh][n] = (f32x4){0.f,0.f,0.f,0.f};

    #pragma unroll
    for (int sh = 0; sh < 2; ++sh)
      #pragma unroll
      for (int n = 0; n < 2; ++n)
        #pragma unroll
        for (int kd = 0; kd < 4; ++kd) {
          bf16x8 bf = *(const bf16x8*)&lds_k[sh][n*16 + l15][kd*32 + quad*8];
          sacc[sh][n] = __builtin_amdgcn_mfma_f32_16x16x32_bf16(qf[sh][kd], bf, sacc[sh][n], 0, 0, 0);
        }

    const int qrow0 = qb + w*16 + quad*4;
    const int c0 = kbt + l15, c1 = c0 + 16;
    #pragma unroll
    for (int sh = 0; sh < 2; ++sh) {
      #pragma unroll
      for (int r = 0; r < 4; ++r) {
        float s0 = sacc[sh][0][r] * SCALE;
        float s1 = sacc[sh][1][r] * SCALE;
        const int qr = qrow0 + r;
        if (c0 > qr) s0 = -1e30f;
        if (c1 > qr) s1 = -1e30f;
        float mx = fmaxf(s0, s1);
        #pragma unroll
        for (int off = 1; off < 16; off <<= 1)
          mx = fmaxf(mx, __shfl_xor(mx, off));
        const float mnew = fmaxf(mst[sh][r], mx);
        const float alpha = __expf(mst[sh][r] - mnew);
        mst[sh][r] = mnew;
        const float p0 = __expf(s0 - mnew);
        const float p1 = __expf(s1 - mnew);
        float rs = p0 + p1;
        #pragma unroll
        for (int off = 1; off < 16; off <<= 1)
          rs += __shfl_xor(rs, off);
        lst[sh][r] = lst[sh][r] * alpha + rs;
        #pragma unroll
        for (int nt = 0; nt < 8; ++nt)
          oacc[sh][nt][r] *= alpha;
        lds_p[w][sh][quad*4 + r][l15]      = (__bf16)p0;
        lds_p[w][sh][quad*4 + r][l15 + 16] = (__bf16)p1;
      }
    }

    {
      bf16x8 pf0 = *(const bf16x8*)&lds_p[w][0][l15][quad*8];
      bf16x8 pf1 = *(const bf16x8*)&lds_p[w][1][l15][quad*8];
      #pragma unroll
      for (int nt = 0; nt < 8; ++nt) {
        bf16x8 vf = *(const bf16x8*)&lds_vt[nt*16 + l15][quad*8];
        oacc[0][nt] = __builtin_amdgcn_mfma_f32_16x16x32_bf16(pf0, vf, oacc[0][nt], 0, 0, 0);
        oacc[1][nt] = __builtin_amdgcn_mfma_f32_16x16x32_bf16(pf1, vf, oacc[1][nt], 0, 0, 0);
      }
    }
    __syncthreads();
  }

  const int qrow0 = qb + w*16 + quad*4;
  float* obase = Obuf + (size_t)(b*NH + h) * SEQ * DH;
  float sum = 0.f, ss = 0.f;
  #pragma unroll
  for (int r = 0; r < 4; ++r) {
    const float i0 = 1.0f / lst[0][r];
    const float i1 = lam / lst[1][r];
    float* orow = obase + (size_t)(qrow0 + r) * DH + l15;
    #pragma unroll
    for (int nt = 0; nt < 8; ++nt) {
      const float val = oacc[0][nt][r] * i0 - oacc[1][nt][r] * i1;
      orow[nt*16] = val;
      sum += val;
      ss  += val * val;
    }
  }
  #pragma unroll
  for (int off = 1; off < 64; off <<= 1) {
    sum += __shfl_xor(sum, off);
    ss  += __shfl_xor(ss, off);
  }
  if (lane == 0) {
    atomicAdd(&stats[2*(b*NH + h)],     sum);
    atomicAdd(&stats[2*(b*NH + h) + 1], ss);
  }
}

// ---------------- GroupNorm epilogue ---------------------------------------
__global__ __launch_bounds__(256) void norm_kernel(
    float* __restrict__ Obuf, const float* __restrict__ stats,
    const float* __restrict__ gw, const float* __restrict__ gb)
{
  const int idx = (blockIdx.x * 256 + threadIdx.x) * 4;
  const int bh = idx >> 18;
  const int local = idx & 262143;
  const float inv = 1.0f / 262144.0f;
  const float mean = stats[2*bh] * inv;
  const float var  = stats[2*bh + 1] * inv - mean * mean;
  const float rstd = rsqrtf(var + 1e-5f);
  const int c = ((bh & 7) << 7) + (local >> 11);
  const float wq = gw[c] * rstd;
  const float bq = gb[c];
  float4 o = *(const float4*)(Obuf + idx);
  float4 r;
  r.x = ((o.x - mean) * wq + bq) * 0.2f;
  r.y = ((o.y - mean) * wq + bq) * 0.2f;
  r.z = ((o.z - mean) * wq + bq) * 0.2f;
  r.w = ((o.w - mean) * wq + bq) * 0.2f;
  *(float4*)(Obuf + idx) = r;
}

extern "C" void kernel_launch(void* const* d_in, const int* in_sizes, int n_in,
                              void* d_out, int out_size, void* d_ws, size_t ws_size,
                              hipStream_t stream) {
  const float* q   = (const float*)d_in[0];
  const float* k   = (const float*)d_in[1];
  const float* v   = (const float*)d_in[2];
  const float* lq1 = (const float*)d_in[3];
  const float* lk1 = (const float*)d_in[4];
  const float* lq2 = (const float*)d_in[5];
  const float* lk2 = (const float*)d_in[6];
  const float* gw  = (const float*)d_in[7];
  const float* gb  = (const float*)d_in[8];
  float* out = (float*)d_out;
  float* stats = (float*)d_ws;

  if (ws_size >= WS_NEED) {
    __bf16* Kb  = (__bf16*)((char*)d_ws + OFF_KB);
    __bf16* Vtb = (__bf16*)((char*)d_ws + OFF_VT);

    prep_kernel<<<8192, 256, 0, stream>>>(k, v, Kb, Vtb, stats);

    attn2_kernel<<<dim3(32, 16), 256, 0, stream>>>(q, Kb, Vtb,
        lq1, lk1, lq2, lk2, out, stats);
  } else {
    (void)hipMemsetAsync(d_ws, 0, 256, stream);
    attn_fb_kernel<<<dim3(32, NH, 2), 256, 0, stream>>>(q, k, v,
        lq1, lk1, lq2, lk2, out, stats);
  }

  const int total = 2 * NH * SEQ * DH;
  norm_kernel<<<total / 1024, 256, 0, stream>>>(out, stats, gw, gb);
}

// Round 6
// 206.786 us; speedup vs baseline: 2.7094x; 1.0472x over previous
//
#include <hip/hip_runtime.h>
#include <hip/hip_bf16.h>
#include <cstddef>
#include <cstdint>

// ---------------------------------------------------------------------------
// Differential attention (PraxisAttention).
// Round 6: dual-group blocks. 512 threads = 8 waves; group 0 (waves 0-3)
// does even K-steps, group 1 (waves 4-7) odd K-steps (fixed-m ghostmax makes
// steps additive), each group with its own double-buffered LDS staging
// (116 KB -> exactly 1 block/CU, 8 waves/CU guaranteed). Grid = 512 tiles
// longest-first -> 256-deep backfill queue gives LPT balance with no
// dispatch-mapping assumptions. Groups combine O/l in LDS at epilogue.
// ---------------------------------------------------------------------------

typedef __bf16 bf16x8 __attribute__((ext_vector_type(8)));
typedef __bf16 bf16x4 __attribute__((ext_vector_type(4)));
typedef float f32x4 __attribute__((ext_vector_type(4)));

constexpr int SEQ = 2048;
constexpr int DH  = 128;
constexpr int NH  = 8;
constexpr int NH2 = 16;
constexpr float SCALE = 0.088388347648318447f; // 1/sqrt(128)

// ws layout (bytes):
//   [0,256)        : stats (sum, sumsq) per (b,h)
//   [4096, +16MB)  : Kb  bf16               [b][h2][t][d]
//   [.., +8MB)     : Vtb bf16               [b][h][d][t]
constexpr size_t QK_ELEMS = (size_t)2 * NH2 * SEQ * DH;   // 8,388,608
constexpr size_t V_ELEMS  = (size_t)2 * NH  * SEQ * DH;   // 4,194,304
constexpr size_t OFF_KB   = 4096;
constexpr size_t OFF_VT   = OFF_KB + QK_ELEMS * 2;
constexpr size_t WS_NEED  = OFF_VT + V_ELEMS * 2;

__device__ __forceinline__ void load_lds16(const void* g, void* l) {
  __builtin_amdgcn_global_load_lds(
      (const __attribute__((address_space(1))) uint32_t*)g,
      (__attribute__((address_space(3))) uint32_t*)l, 16, 0, 0);
}

__device__ __forceinline__ bf16x8 cvt8(float4 a, float4 b) {
  bf16x8 r;
  r[0] = (__bf16)a.x; r[1] = (__bf16)a.y; r[2] = (__bf16)a.z; r[3] = (__bf16)a.w;
  r[4] = (__bf16)b.x; r[5] = (__bf16)b.y; r[6] = (__bf16)b.z; r[7] = (__bf16)b.w;
  return r;
}

// ---------------- fused pre-pass: K->bf16, V->V^T bf16, stats zero ---------
__global__ __launch_bounds__(256) void prep_kernel(
    const float* __restrict__ k, const float* __restrict__ v,
    __bf16* __restrict__ Kb, __bf16* __restrict__ Vtb,
    float* __restrict__ stats)
{
  __shared__ float tile[32][33];
  const int id = blockIdx.x;
  if (id == 0 && threadIdx.x < 64) stats[threadIdx.x] = 0.f;
  if (id < 4096) {
    const size_t i = ((size_t)id * 256 + threadIdx.x) * 8;
    float4 a = *(const float4*)(k + i);
    float4 b = *(const float4*)(k + i + 4);
    *(bf16x8*)(Kb + i) = cvt8(a, b);
  } else {
    const int vid = id - 4096;
    const int tt = vid & 63, dt = (vid >> 6) & 3, bh = vid >> 8;
    const int tr = threadIdx.x >> 3, tc = (threadIdx.x & 7) * 4;
    const float* src = v + ((size_t)bh * SEQ + tt * 32) * DH + dt * 32;
    float4 f = *(const float4*)(src + (size_t)tr * DH + tc);
    tile[tr][tc + 0] = f.x; tile[tr][tc + 1] = f.y;
    tile[tr][tc + 2] = f.z; tile[tr][tc + 3] = f.w;
    __syncthreads();
    __bf16* dst = Vtb + ((size_t)bh * DH + dt * 32 + tr) * SEQ + tt * 32 + tc;
    bf16x4 o;
    o[0] = (__bf16)tile[tc + 0][tr];
    o[1] = (__bf16)tile[tc + 1][tr];
    o[2] = (__bf16)tile[tc + 2][tr];
    o[3] = (__bf16)tile[tc + 3][tr];
    *(bf16x4*)dst = o;
  }
}

// ---------------- main attention kernel (dual-group) -----------------------
__global__ __launch_bounds__(512, 1) void attn3_kernel(
    const float* __restrict__ Qf, const __bf16* __restrict__ Kb,
    const __bf16* __restrict__ Vtb,
    const float* __restrict__ lq1, const float* __restrict__ lk1,
    const float* __restrict__ lq2, const float* __restrict__ lk2,
    float* __restrict__ Obuf, float* __restrict__ stats)
{
  // per-group double-buffered staging (packed for global_load_lds, XOR swizzle)
  __shared__ __align__(16) __bf16 ldsK[2][2][2][32][128];  // [grp][buf][sh][kr][d] 64KB
  __shared__ __align__(16) __bf16 ldsVt[2][2][128][32];    // [grp][buf][d][t]     32KB
  __shared__ __align__(16) __bf16 ldsP[2][4][2][16][40];   // [grp][wave][sh][r][t] 20KB
  __shared__ float ldsL[4][2][16];                         // group-1 l partials

  const int qt = 31 - (int)(blockIdx.x >> 4);  // longest tiles first
  const int bh = blockIdx.x & 15;
  const int b = bh >> 3, h = bh & 7;
  const int tid = threadIdx.x;
  const int g  = tid >> 8;        // group 0: even steps, group 1: odd steps
  const int t2 = tid & 255;
  const int w = t2 >> 6, lane = tid & 63;
  const int l15 = lane & 15, quad = lane >> 4;

  // ---- lambda scalar ----
  float a1 = lq1[lane]*lk1[lane] + lq1[lane+64]*lk1[lane+64];
  float a2 = lq2[lane]*lk2[lane] + lq2[lane+64]*lk2[lane+64];
  #pragma unroll
  for (int off = 1; off < 64; off <<= 1) {
    a1 += __shfl_xor(a1, off);
    a2 += __shfl_xor(a2, off);
  }
  const float lam = __expf(a1) - __expf(a2) + 0.8f;

  const size_t headQK = (size_t)(b*NH2 + 2*h) * SEQ * DH;
  const float*  Qh  = Qf + headQK;
  const __bf16* Kh  = Kb + headQK;
  const __bf16* Vth = Vtb + (size_t)(b*NH + h) * DH * SEQ;

  // ---- per-lane staging source offsets (element units, swizzled) ----
  size_t goffK[4];
  #pragma unroll
  for (int i = 0; i < 4; ++i) {
    const int R  = w*16 + i*4 + quad;      // flat row 0..63
    const int sh = R >> 5, kr = R & 31;
    const int cs = lane & 15;              // LDS chunk slot
    goffK[i] = ((size_t)sh * SEQ + kr) * DH + ((cs ^ (kr & 15)) * 8);
  }
  size_t goffV[2];
  #pragma unroll
  for (int i = 0; i < 2; ++i) {
    const int d  = w*32 + i*16 + ((t2 & 63) >> 2);
    const int cs = lane & 3;
    goffV[i] = (size_t)d * SEQ + ((cs ^ (d & 3)) * 8);
  }

  __bf16* ldsKg = &ldsK[g][0][0][0][0];
  __bf16* ldsVg = &ldsVt[g][0][0][0];

  const int qb = qt * 64;
  const int nph = qt + 1;        // phases per group (steps st = 2*j + g)

  // Q fragments: fp32 global -> scale -> bf16 A-layout (both groups same rows)
  const int qrow = qb + w*16 + l15;
  bf16x8 qf[2][4];
  #pragma unroll
  for (int sh = 0; sh < 2; ++sh) {
    const float* src = Qh + (size_t)sh*SEQ*DH + (size_t)qrow*DH + quad*8;
    #pragma unroll
    for (int kd = 0; kd < 4; ++kd) {
      float4 f0 = *(const float4*)(src + kd*32);
      float4 f1 = *(const float4*)(src + kd*32 + 4);
      f0.x *= SCALE; f0.y *= SCALE; f0.z *= SCALE; f0.w *= SCALE;
      f1.x *= SCALE; f1.y *= SCALE; f1.z *= SCALE; f1.w *= SCALE;
      qf[sh][kd] = cvt8(f0, f1);
    }
  }

  f32x4 oacc[2][8];
  float lsum[2][4];
  #pragma unroll
  for (int sh = 0; sh < 2; ++sh) {
    #pragma unroll
    for (int nt = 0; nt < 8; ++nt) oacc[sh][nt] = (f32x4){0.f,0.f,0.f,0.f};
    #pragma unroll
    for (int r = 0; r < 4; ++r) lsum[sh][r] = 0.f;
  }

  // stage phase 0 (step g) into buf 0
  {
    const __bf16* kg = Kh + (size_t)g * 32 * DH;
    #pragma unroll
    for (int i = 0; i < 4; ++i)
      load_lds16(kg + goffK[i], ldsKg + w*2048 + i*512);
    const __bf16* vg = Vth + g * 32;
    #pragma unroll
    for (int i = 0; i < 2; ++i)
      load_lds16(vg + goffV[i], ldsVg + w*1024 + i*512);
  }
  __syncthreads();

  for (int j = 0; j < nph; ++j) {
    const int cur = j & 1;
    const int kbt = (2*j + g) * 32;

    // async prefetch this group's next step (st+2) into the other buffer
    if (j + 1 < nph) {
      const int nxt = cur ^ 1;
      const __bf16* kg = Kh + (size_t)(kbt + 64) * DH;
      #pragma unroll
      for (int i = 0; i < 4; ++i)
        load_lds16(kg + goffK[i], ldsKg + (size_t)nxt*8192 + w*2048 + i*512);
      const __bf16* vg = Vth + (kbt + 64);
      #pragma unroll
      for (int i = 0; i < 2; ++i)
        load_lds16(vg + goffV[i], ldsVg + (size_t)nxt*4096 + w*1024 + i*512);
    }

    // ---- S = Q K^T ----
    f32x4 sacc[2][2];
    #pragma unroll
    for (int sh = 0; sh < 2; ++sh)
      #pragma unroll
      for (int n = 0; n < 2; ++n)
        sacc[sh][n] = (f32x4){0.f,0.f,0.f,0.f};
    #pragma unroll
    for (int sh = 0; sh < 2; ++sh)
      #pragma unroll
      for (int n = 0; n < 2; ++n)
        #pragma unroll
        for (int kd = 0; kd < 4; ++kd) {
          bf16x8 kf = *(const bf16x8*)&ldsK[g][cur][sh][n*16 + l15][((kd*4 + quad) ^ l15) * 8];
          sacc[sh][n] = __builtin_amdgcn_mfma_f32_16x16x32_bf16(qf[sh][kd], kf, sacc[sh][n], 0, 0, 0);
        }

    // ---- fixed-m ghostmax: p = exp(s) (masked), accumulate l per-lane ----
    const int qrow0 = qb + w*16 + quad*4;
    #pragma unroll
    for (int sh = 0; sh < 2; ++sh)
      #pragma unroll
      for (int r = 0; r < 4; ++r) {
        const int qr = qrow0 + r;
        const float p0 = (kbt + l15      <= qr) ? __expf(sacc[sh][0][r]) : 0.f;
        const float p1 = (kbt + l15 + 16 <= qr) ? __expf(sacc[sh][1][r]) : 0.f;
        lsum[sh][r] += p0 + p1;
        ldsP[g][w][sh][quad*4 + r][l15]      = (__bf16)p0;
        ldsP[g][w][sh][quad*4 + r][l15 + 16] = (__bf16)p1;
      }

    // ---- O += P V ----
    {
      bf16x8 pf0 = *(const bf16x8*)&ldsP[g][w][0][l15][quad*8];
      bf16x8 pf1 = *(const bf16x8*)&ldsP[g][w][1][l15][quad*8];
      #pragma unroll
      for (int nt = 0; nt < 8; ++nt) {
        bf16x8 vf = *(const bf16x8*)&ldsVt[g][cur][nt*16 + l15][(quad ^ (l15 & 3)) * 8];
        oacc[0][nt] = __builtin_amdgcn_mfma_f32_16x16x32_bf16(pf0, vf, oacc[0][nt], 0, 0, 0);
        oacc[1][nt] = __builtin_amdgcn_mfma_f32_16x16x32_bf16(pf1, vf, oacc[1][nt], 0, 0, 0);
      }
    }
    __syncthreads();
  }

  // ---- epilogue: combine groups via LDS (fixed-m partials are additive) ----
  float lr[2][4];
  #pragma unroll
  for (int sh = 0; sh < 2; ++sh)
    #pragma unroll
    for (int r = 0; r < 4; ++r) {
      float vsum = lsum[sh][r];
      #pragma unroll
      for (int off = 1; off < 16; off <<= 1) vsum += __shfl_xor(vsum, off);
      lr[sh][r] = vsum;
    }

  float* Oscr = (float*)&ldsK[0][0][0][0][0];   // 64 KB scratch (staging done)
  if (g == 1) {
    #pragma unroll
    for (int sh = 0; sh < 2; ++sh)
      #pragma unroll
      for (int nt = 0; nt < 8; ++nt)
        #pragma unroll
        for (int r = 0; r < 4; ++r)
          Oscr[((w*2 + sh)*16 + quad*4 + r)*128 + nt*16 + l15] = oacc[sh][nt][r];
    if (l15 == 0) {
      #pragma unroll
      for (int sh = 0; sh < 2; ++sh)
        #pragma unroll
        for (int r = 0; r < 4; ++r)
          ldsL[w][sh][quad*4 + r] = lr[sh][r];
    }
  }
  __syncthreads();

  if (g == 0) {
    const int qrow0 = qb + w*16 + quad*4;
    float* obase = Obuf + (size_t)(b*NH + h) * SEQ * DH;
    float sum = 0.f, ss = 0.f;
    #pragma unroll
    for (int r = 0; r < 4; ++r) {
      const float l0 = lr[0][r] + ldsL[w][0][quad*4 + r] + 1.0f;
      const float l1 = lr[1][r] + ldsL[w][1][quad*4 + r] + 1.0f;
      const float i0 = 1.0f / l0;
      const float i1 = lam / l1;
      float* orow = obase + (size_t)(qrow0 + r) * DH + l15;
      #pragma unroll
      for (int nt = 0; nt < 8; ++nt) {
        const float o0 = oacc[0][nt][r] + Oscr[((w*2 + 0)*16 + quad*4 + r)*128 + nt*16 + l15];
        const float o1 = oacc[1][nt][r] + Oscr[((w*2 + 1)*16 + quad*4 + r)*128 + nt*16 + l15];
        const float val = o0 * i0 - o1 * i1;
        orow[nt*16] = val;
        sum += val;
        ss  += val * val;
      }
    }
    #pragma unroll
    for (int off = 1; off < 64; off <<= 1) {
      sum += __shfl_xor(sum, off);
      ss  += __shfl_xor(ss, off);
    }
    if (lane == 0) {
      atomicAdd(&stats[2*(b*NH + h)],     sum);
      atomicAdd(&stats[2*(b*NH + h) + 1], ss);
    }
  }
}

// ---------------- fallback (round-1) attention kernel ----------------------
__global__ __launch_bounds__(256) void attn_fb_kernel(
    const float* __restrict__ q, const float* __restrict__ k,
    const float* __restrict__ v,
    const float* __restrict__ lq1, const float* __restrict__ lk1,
    const float* __restrict__ lq2, const float* __restrict__ lk2,
    float* __restrict__ Obuf, float* __restrict__ stats)
{
  __shared__ __align__(16) __bf16 lds_k[2][32][136];
  __shared__ __align__(16) __bf16 lds_vt[128][40];
  __shared__ __align__(16) __bf16 lds_p[4][2][16][40];

  const int qt = blockIdx.x, h = blockIdx.y, b = blockIdx.z;
  const int qb = qt * 64;
  const int tid = threadIdx.x;
  const int w = tid >> 6, lane = tid & 63;
  const int l15 = lane & 15, quad = lane >> 4;

  float a1 = lq1[lane]*lk1[lane] + lq1[lane+64]*lk1[lane+64];
  float a2 = lq2[lane]*lk2[lane] + lq2[lane+64]*lk2[lane+64];
  #pragma unroll
  for (int off = 1; off < 64; off <<= 1) {
    a1 += __shfl_xor(a1, off);
    a2 += __shfl_xor(a2, off);
  }
  const float lam = __expf(a1) - __expf(a2) + 0.8f;

  const float* qh0 = q + (size_t)(b*NH2 + 2*h) * SEQ * DH;
  const float* qh1 = qh0 + (size_t)SEQ * DH;
  const float* kh0 = k + (size_t)(b*NH2 + 2*h) * SEQ * DH;
  const float* kh1 = kh0 + (size_t)SEQ * DH;
  const float* vh  = v + (size_t)(b*NH + h) * SEQ * DH;

  bf16x8 qf[2][4];
  {
    const int qrow = qb + w*16 + l15;
    #pragma unroll
    for (int sh = 0; sh < 2; ++sh) {
      const float* src = (sh ? qh1 : qh0) + (size_t)qrow * DH + quad*8;
      #pragma unroll
      for (int kd = 0; kd < 4; ++kd) {
        float4 f0 = *(const float4*)(src + kd*32);
        float4 f1 = *(const float4*)(src + kd*32 + 4);
        qf[sh][kd] = cvt8(f0, f1);
      }
    }
  }

  f32x4 oacc[2][8];
  #pragma unroll
  for (int sh = 0; sh < 2; ++sh)
    #pragma unroll
    for (int nt = 0; nt < 8; ++nt)
      oacc[sh][nt] = (f32x4){0.f,0.f,0.f,0.f};

  float mst[2][4] = {{0.f,0.f,0.f,0.f},{0.f,0.f,0.f,0.f}};
  float lst[2][4] = {{1.f,1.f,1.f,1.f},{1.f,1.f,1.f,1.f}};

  const int krow = tid >> 2, ksh = krow >> 5, kr = krow & 31;
  const int kd0 = (tid & 3) * 32;
  const float* ksrc0 = (ksh ? kh1 : kh0) + kd0;
  const int vt = tid >> 3, vd = (tid & 7) * 16;

  const int nsteps = (qb + 64) / 32;
  for (int st = 0; st < nsteps; ++st) {
    const int kbt = st * 32;
    {
      const float* sp = ksrc0 + (size_t)(kbt + kr) * DH;
      #pragma unroll
      for (int c = 0; c < 4; ++c) {
        float4 f0 = *(const float4*)(sp + c*8);
        float4 f1 = *(const float4*)(sp + c*8 + 4);
        *(bf16x8*)&lds_k[ksh][kr][kd0 + c*8] = cvt8(f0, f1);
      }
      const float* vp = vh + (size_t)(kbt + vt) * DH + vd;
      #pragma unroll
      for (int c = 0; c < 4; ++c) {
        float4 f = *(const float4*)(vp + c*4);
        lds_vt[vd + c*4 + 0][vt] = (__bf16)f.x;
        lds_vt[vd + c*4 + 1][vt] = (__bf16)f.y;
        lds_vt[vd + c*4 + 2][vt] = (__bf16)f.z;
        lds_vt[vd + c*4 + 3][vt] = (__bf16)f.w;
      }
    }
    __syncthreads();

    f32x4 sacc[2][2];
    #pragma unroll
    for (int sh = 0; sh < 2; ++sh)
      #pragma unroll
      for (int n = 0; n < 2; ++n)
        sacc[sh][n] = (f32x4){0.f,0.f,0.f,0.f};

    #pragma unroll
    for (int sh = 0; sh < 2; ++sh)
      #pragma unroll
      for (int n = 0; n < 2; ++n)
        #pragma unroll
        for (int kd = 0; kd < 4; ++kd) {
          bf16x8 bf = *(const bf16x8*)&lds_k[sh][n*16 + l15][kd*32 + quad*8];
          sacc[sh][n] = __builtin_amdgcn_mfma_f32_16x16x32_bf16(qf[sh][kd], bf, sacc[sh][n], 0, 0, 0);
        }

    const int qrow0 = qb + w*16 + quad*4;
    const int c0 = kbt + l15, c1 = c0 + 16;
    #pragma unroll
    for (int sh = 0; sh < 2; ++sh) {
      #pragma unroll
      for (int r = 0; r < 4; ++r) {
        float s0 = sacc[sh][0][r] * SCALE;
        float s1 = sacc[sh][1][r] * SCALE;
        const int qr = qrow0 + r;
        if (c0 > qr) s0 = -1e30f;
        if (c1 > qr) s1 = -1e30f;
        float mx = fmaxf(s0, s1);
        #pragma unroll
        for (int off = 1; off < 16; off <<= 1)
          mx = fmaxf(mx, __shfl_xor(mx, off));
        const float mnew = fmaxf(mst[sh][r], mx);
        const float alpha = __expf(mst[sh][r] - mnew);
        mst[sh][r] = mnew;
        const float p0 = __expf(s0 - mnew);
        const float p1 = __expf(s1 - mnew);
        float rs = p0 + p1;
        #pragma unroll
        for (int off = 1; off < 16; off <<= 1)
          rs += __shfl_xor(rs, off);
        lst[sh][r] = lst[sh][r] * alpha + rs;
        #pragma unroll
        for (int nt = 0; nt < 8; ++nt)
          oacc[sh][nt][r] *= alpha;
        lds_p[w][sh][quad*4 + r][l15]      = (__bf16)p0;
        lds_p[w][sh][quad*4 + r][l15 + 16] = (__bf16)p1;
      }
    }

    {
      bf16x8 pf0 = *(const bf16x8*)&lds_p[w][0][l15][quad*8];
      bf16x8 pf1 = *(const bf16x8*)&lds_p[w][1][l15][quad*8];
      #pragma unroll
      for (int nt = 0; nt < 8; ++nt) {
        bf16x8 vf = *(const bf16x8*)&lds_vt[nt*16 + l15][quad*8];
        oacc[0][nt] = __builtin_amdgcn_mfma_f32_16x16x32_bf16(pf0, vf, oacc[0][nt], 0, 0, 0);
        oacc[1][nt] = __builtin_amdgcn_mfma_f32_16x16x32_bf16(pf1, vf, oacc[1][nt], 0, 0, 0);
      }
    }
    __syncthreads();
  }

  const int qrow0 = qb + w*16 + quad*4;
  float* obase = Obuf + (size_t)(b*NH + h) * SEQ * DH;
  float sum = 0.f, ss = 0.f;
  #pragma unroll
  for (int r = 0; r < 4; ++r) {
    const float i0 = 1.0f / lst[0][r];
    const float i1 = lam / lst[1][r];
    float* orow = obase + (size_t)(qrow0 + r) * DH + l15;
    #pragma unroll
    for (int nt = 0; nt < 8; ++nt) {
      const float val = oacc[0][nt][r] * i0 - oacc[1][nt][r] * i1;
      orow[nt*16] = val;
      sum += val;
      ss  += val * val;
    }
  }
  #pragma unroll
  for (int off = 1; off < 64; off <<= 1) {
    sum += __shfl_xor(sum, off);
    ss  += __shfl_xor(ss, off);
  }
  if (lane == 0) {
    atomicAdd(&stats[2*(b*NH + h)],     sum);
    atomicAdd(&stats[2*(b*NH + h) + 1], ss);
  }
}

// ---------------- GroupNorm epilogue ---------------------------------------
__global__ __launch_bounds__(256) void norm_kernel(
    float* __restrict__ Obuf, const float* __restrict__ stats,
    const float* __restrict__ gw, const float* __restrict__ gb)
{
  const int idx = (blockIdx.x * 256 + threadIdx.x) * 4;
  const int bh = idx >> 18;
  const int local = idx & 262143;
  const float inv = 1.0f / 262144.0f;
  const float mean = stats[2*bh] * inv;
  const float var  = stats[2*bh + 1] * inv - mean * mean;
  const float rstd = rsqrtf(var + 1e-5f);
  const int c = ((bh & 7) << 7) + (local >> 11);
  const float wq = gw[c] * rstd;
  const float bq = gb[c];
  float4 o = *(const float4*)(Obuf + idx);
  float4 r;
  r.x = ((o.x - mean) * wq + bq) * 0.2f;
  r.y = ((o.y - mean) * wq + bq) * 0.2f;
  r.z = ((o.z - mean) * wq + bq) * 0.2f;
  r.w = ((o.w - mean) * wq + bq) * 0.2f;
  *(float4*)(Obuf + idx) = r;
}

extern "C" void kernel_launch(void* const* d_in, const int* in_sizes, int n_in,
                              void* d_out, int out_size, void* d_ws, size_t ws_size,
                              hipStream_t stream) {
  const float* q   = (const float*)d_in[0];
  const float* k   = (const float*)d_in[1];
  const float* v   = (const float*)d_in[2];
  const float* lq1 = (const float*)d_in[3];
  const float* lk1 = (const float*)d_in[4];
  const float* lq2 = (const float*)d_in[5];
  const float* lk2 = (const float*)d_in[6];
  const float* gw  = (const float*)d_in[7];
  const float* gb  = (const float*)d_in[8];
  float* out = (float*)d_out;
  float* stats = (float*)d_ws;

  if (ws_size >= WS_NEED) {
    __bf16* Kb  = (__bf16*)((char*)d_ws + OFF_KB);
    __bf16* Vtb = (__bf16*)((char*)d_ws + OFF_VT);

    prep_kernel<<<8192, 256, 0, stream>>>(k, v, Kb, Vtb, stats);

    attn3_kernel<<<512, 512, 0, stream>>>(q, Kb, Vtb,
        lq1, lk1, lq2, lk2, out, stats);
  } else {
    (void)hipMemsetAsync(d_ws, 0, 256, stream);
    attn_fb_kernel<<<dim3(32, NH, 2), 256, 0, stream>>>(q, k, v,
        lq1, lk1, lq2, lk2, out, stats);
  }

  const int total = 2 * NH * SEQ * DH;
  norm_kernel<<<total / 1024, 256, 0, stream>>>(out, stats, gw, gb);
}